// Round 11
// baseline (249.806 us; speedup 1.0000x reference)
//
#include <hip/hip_runtime.h>
#include <hip/hip_bf16.h>

// Problem constants
#define BB 2
#define SS 1024
#define DD 768
#define HH 12
#define HD 64
#define DFF 3072
#define EPS 1e-5f
#define BS2 (BB * SS)            // 2048
#define BSD ((size_t)BS2 * DD)   // 2048*768

typedef unsigned short ushort_t;
typedef unsigned char uchar_t;
using short8 = __attribute__((ext_vector_type(8))) short;
using f32x4  = __attribute__((ext_vector_type(4))) float;

// s_waitcnt immediates (gfx9 encoding)
#define WAITCNT_LGKM0 0xC07F     // lgkmcnt(0), vmcnt/expcnt unconstrained

__device__ __forceinline__ ushort_t f2bf_rne(float f) {
    union { float f; unsigned u; } x; x.f = f;
    unsigned r = x.u + 0x7fff + ((x.u >> 16) & 1);
    return (ushort_t)(r >> 16);
}
__device__ __forceinline__ float bf2f(short u) {
    union { unsigned i; float f; } x;
    x.i = ((unsigned)(ushort_t)u) << 16;
    return x.f;
}
// (o0 + o1) * inv, elementwise bf16x8
__device__ __forceinline__ short8 mergeo(short8 a, short8 b, float inv) {
    short8 o;
#pragma unroll
    for (int i = 0; i < 8; ++i)
        o[i] = (short)f2bf_rne((bf2f(a[i]) + bf2f(b[i])) * inv);
    return o;
}

// fp32 -> bf16 cvt of one float4-quad per thread
__device__ __forceinline__ void cvt_quad(const float* __restrict__ src, int off,
                                         ushort_t* __restrict__ dst, int i) {
    float4 v = ((const float4*)src)[off];
    ushort4 o;
    o.x = f2bf_rne(v.x); o.y = f2bf_rne(v.y);
    o.z = f2bf_rne(v.z); o.w = f2bf_rne(v.w);
    ((ushort4*)dst)[i] = o;
}

// ---------------------------------------------------------------------------
// prep1: ONLY what QKV needs — qkv_w cvt (1728 blocks) + LN1 (2048 blocks).
// codes packing and o_w/w1/w2 cvt are shadow-batched into later launches.
// ---------------------------------------------------------------------------
#define P1_CVT (3 * DD * DD / 4 / 256)   // 1728
#define P1_LN  BS2                        // 2048

__global__ __launch_bounds__(256) void prep1_kernel(
    const float* __restrict__ qkv_w, ushort_t* __restrict__ qkvw_bf,
    const float* __restrict__ x, const float* __restrict__ g,
    const float* __restrict__ b, ushort_t* __restrict__ y)
{
    const int bx = blockIdx.x;
    const int t  = threadIdx.x;
    if (bx < P1_CVT) {
        int i = bx * 256 + t;
        cvt_quad(qkv_w, i, qkvw_bf, i);
        return;
    }
    // ---- LN1 ----
    const int row = bx - P1_CVT;
    const float* xr = x + (size_t)row * DD;
    float s = 0.f, ss = 0.f;
    for (int i = t; i < DD; i += 256) {
        float v = xr[i];
        s += v; ss += v * v;
    }
    for (int off = 32; off; off >>= 1) {
        s  += __shfl_down(s,  off);
        ss += __shfl_down(ss, off);
    }
    __shared__ float reds[4], redss[4], bc[2];
    if ((t & 63) == 0) { reds[t >> 6] = s; redss[t >> 6] = ss; }
    __syncthreads();
    if (t == 0) {
        float S1 = reds[0] + reds[1] + reds[2] + reds[3];
        float S2 = redss[0] + redss[1] + redss[2] + redss[3];
        float mean = S1 / DD;
        float var = S2 / DD - mean * mean;
        bc[0] = mean;
        bc[1] = rsqrtf(var + EPS);
    }
    __syncthreads();
    float mean = bc[0], inv = bc[1];
    ushort_t* yr = y + (size_t)row * DD;
    for (int i = t; i < DD; i += 256) {
        yr[i] = f2bf_rne((xr[i] - mean) * inv * g[i] + b[i]);
    }
}

// ---------------------------------------------------------------------------
// Fused: resid = inp + p0 + p1 (bf16 partials) ; h_bf = LN(resid).
// ---------------------------------------------------------------------------
__global__ __launch_bounds__(256) void merge2_ln_kernel(
    const ushort_t* __restrict__ part, const float* __restrict__ inp,
    const float* __restrict__ g, const float* __restrict__ b,
    float* __restrict__ resid, ushort_t* __restrict__ h_bf)
{
    const int row = blockIdx.x;
    const int t = threadIdx.x;
    float4 v = make_float4(0.f, 0.f, 0.f, 0.f);
    const size_t idx = (size_t)row * (DD / 4) + t;
    if (t < DD / 4) {
        v = ((const float4*)inp)[idx];
        ushort4 p0 = ((const ushort4*)part)[idx];
        ushort4 p1 = ((const ushort4*)(part + BSD))[idx];
        v.x += bf2f(p0.x) + bf2f(p1.x);
        v.y += bf2f(p0.y) + bf2f(p1.y);
        v.z += bf2f(p0.z) + bf2f(p1.z);
        v.w += bf2f(p0.w) + bf2f(p1.w);
        ((float4*)resid)[idx] = v;
    }
    float s  = v.x + v.y + v.z + v.w;
    float ss = v.x * v.x + v.y * v.y + v.z * v.z + v.w * v.w;
    for (int off = 32; off; off >>= 1) {
        s  += __shfl_down(s,  off);
        ss += __shfl_down(ss, off);
    }
    __shared__ float reds[4], redss[4], bc[2];
    if ((t & 63) == 0) { reds[t >> 6] = s; redss[t >> 6] = ss; }
    __syncthreads();
    if (t == 0) {
        float S1 = reds[0] + reds[1] + reds[2] + reds[3];
        float S2 = redss[0] + redss[1] + redss[2] + redss[3];
        float mean = S1 / DD;
        float var = S2 / DD - mean * mean;
        bc[0] = mean;
        bc[1] = rsqrtf(var + EPS);
    }
    __syncthreads();
    if (t < DD / 4) {
        const float mean = bc[0], inv = bc[1];
        float4 gv = ((const float4*)g)[t];
        float4 bv = ((const float4*)b)[t];
        ushort4 o;
        o.x = f2bf_rne((v.x - mean) * inv * gv.x + bv.x);
        o.y = f2bf_rne((v.y - mean) * inv * gv.y + bv.y);
        o.z = f2bf_rne((v.z - mean) * inv * gv.z + bv.z);
        o.w = f2bf_rne((v.w - mean) * inv * gv.w + bv.w);
        ((ushort4*)h_bf)[idx] = o;
    }
}

// ---------------------------------------------------------------------------
// merge4: out = resid + b2 + sum of 4 bf16 partial slices.
// ---------------------------------------------------------------------------
__global__ __launch_bounds__(256) void merge4_kernel(
    const ushort_t* __restrict__ part, const float* __restrict__ resid,
    const float* __restrict__ b2, float* __restrict__ outp, int n4)
{
    int i = blockIdx.x * 256 + threadIdx.x;
    if (i >= n4) return;
    float4 v = ((const float4*)resid)[i];
    int col4 = (i * 4) % DD;
    float4 bv = *(const float4*)(b2 + col4);
    v.x += bv.x; v.y += bv.y; v.z += bv.z; v.w += bv.w;
#pragma unroll
    for (int z = 0; z < 4; ++z) {
        ushort4 pz = ((const ushort4*)(part + (size_t)z * BSD))[i];
        v.x += bf2f(pz.x); v.y += bf2f(pz.y);
        v.z += bf2f(pz.z); v.w += bf2f(pz.w);
    }
    ((float4*)outp)[i] = v;
}

// ---------------------------------------------------------------------------
// REGISTER-PIPELINED MFMA GEMM BODY (R3 core — best measured), 64x128 tile,
// BK=64, 256 threads = 4 waves, XCD-chunked swizzle with explicit gemm-block
// count `nwg` (the launch may carry extra shadow blocks after the gemm range).
// FUSE_ATT: A is the attention k-split pair merged on the fly (R5/R7 path).
// ---------------------------------------------------------------------------
template <bool RELU, bool OUT_BF16, bool HAS_BIAS, bool PARTIAL, bool FUSE_ATT>
__device__ __forceinline__ void gemm_body(
    int bid, int nwg,
    const ushort_t* __restrict__ A, const ushort_t* __restrict__ W,
    const float* __restrict__ bias, void* __restrict__ Cout,
    const float* __restrict__ lpart,
    int M, int N, int K, int Ksplit, int nx)
{
    __shared__ __align__(16) ushort_t As[512 * 8];    // 8 KB  (64 rows x 8 kq)
    __shared__ __align__(16) ushort_t Bs[1024 * 8];   // 16 KB (128 rows x 8 kq)

    // XCD-chunked decode: nwg % 8 == 0 for all our launches.
    const int swz = (bid & 7) * (nwg >> 3) + (bid >> 3);
    const int by  = swz & 31;          // ny = 32 always (M=2048, 64-row tiles)
    const int t2  = swz >> 5;
    const int bxx = t2 % nx;
    const int bz  = t2 / nx;

    const int t  = threadIdx.x;
    const int n0 = bxx * 128;
    const int m0 = by * 64;
    const int kb = bz * Ksplit;
    const int w  = t >> 6;
    const int l  = t & 63;
    const int wm = (w & 1) * 32;
    const int wn = (w >> 1) * 64;
    const int l15  = l & 15;
    const int quad = l >> 4;

    const ushort_t* gA = A + (size_t)(m0 + (t & 63)) * K + kb + (t >> 6) * 8;
    const ushort_t* gB = W + (size_t)(n0 + (t & 127)) * K + kb + (t >> 7) * 8;

    const float* lp0 = nullptr; const float* lp1 = nullptr;
    const int hbase = kb >> 6;
    if (FUSE_ATT) {
        lp0 = lpart + (size_t)(m0 + (t & 63)) * HH;
        lp1 = lp0 + (size_t)BS2 * HH;
    }

    // prologue: stage tile 0 into registers
    short8 pa0, pa1, ra0, ra1, sa0, sa1;
    float li0 = 0.f, li1 = 0.f;
    if (FUSE_ATT) {
        ra0 = *(const short8*)(gA);
        ra1 = *(const short8*)(gA + 32);
        sa0 = *(const short8*)(gA + BSD);
        sa1 = *(const short8*)(gA + BSD + 32);
        li0 = lp0[hbase];
        li1 = lp1[hbase];
    } else {
        pa0 = *(const short8*)(gA);
        pa1 = *(const short8*)(gA + 32);
    }
    short8 pb0 = *(const short8*)(gB);
    short8 pb1 = *(const short8*)(gB + 16);
    short8 pb2 = *(const short8*)(gB + 32);
    short8 pb3 = *(const short8*)(gB + 48);

    f32x4 acc[2][4] = {};
    const int nIter = Ksplit >> 6;

    for (int it = 0; it < nIter; ++it) {
        // barrier A: all waves finished reading LDS from the previous iter
        __builtin_amdgcn_s_barrier();
        if (FUSE_ATT) {
            const float inv = 1.0f / (li0 + li1);
            pa0 = mergeo(ra0, sa0, inv);
            pa1 = mergeo(ra1, sa1, inv);
        }
        // commit staged tile to LDS (compiler inserts precise vmcnt waits)
        *(short8*)&As[(size_t)t * 8]           = pa0;
        *(short8*)&As[(size_t)(t + 256) * 8]   = pa1;
        *(short8*)&Bs[(size_t)t * 8]           = pb0;
        *(short8*)&Bs[(size_t)(t + 256) * 8]   = pb1;
        *(short8*)&Bs[(size_t)(t + 512) * 8]   = pb2;
        *(short8*)&Bs[(size_t)(t + 768) * 8]   = pb3;
        // issue next tile's loads (in flight across the whole compute phase)
        if (it + 1 < nIter) {
            const int k0 = (it + 1) << 6;
            if (FUSE_ATT) {
                ra0 = *(const short8*)(gA + k0);
                ra1 = *(const short8*)(gA + k0 + 32);
                sa0 = *(const short8*)(gA + k0 + BSD);
                sa1 = *(const short8*)(gA + k0 + BSD + 32);
                li0 = lp0[hbase + it + 1];
                li1 = lp1[hbase + it + 1];
            } else {
                pa0 = *(const short8*)(gA + k0);
                pa1 = *(const short8*)(gA + k0 + 32);
            }
            pb0 = *(const short8*)(gB + k0);
            pb1 = *(const short8*)(gB + k0 + 16);
            pb2 = *(const short8*)(gB + k0 + 32);
            pb3 = *(const short8*)(gB + k0 + 48);
        }
        // my ds_writes done; barrier B: everyone's writes visible
        __builtin_amdgcn_s_waitcnt(WAITCNT_LGKM0);
        __builtin_amdgcn_s_barrier();

#pragma unroll
        for (int ks = 0; ks < 2; ++ks) {
            const ushort_t* aptr = &As[(size_t)((ks * 4 + quad) * 64 + wm + l15) * 8];
            const ushort_t* bptr = &Bs[(size_t)((ks * 4 + quad) * 128 + wn + l15) * 8];
            short8 af[2], bf[4];
#pragma unroll
            for (int i = 0; i < 2; ++i)
                af[i] = *(const short8*)(aptr + (size_t)i * 16 * 8);
#pragma unroll
            for (int j = 0; j < 4; ++j)
                bf[j] = *(const short8*)(bptr + (size_t)j * 16 * 8);
#pragma unroll
            for (int i = 0; i < 2; ++i)
#pragma unroll
                for (int j = 0; j < 4; ++j)
                    acc[i][j] = __builtin_amdgcn_mfma_f32_16x16x32_bf16(
                        af[i], bf[j], acc[i][j], 0, 0, 0);
        }
    }

    // epilogue: C/D layout col=lane&15, row=(lane>>4)*4+reg
    if (PARTIAL) {
        ushort_t* Cp = (ushort_t*)Cout + (size_t)bz * ((size_t)M * N);
#pragma unroll
        for (int i = 0; i < 2; ++i) {
            const int row = m0 + wm + i * 16 + quad * 4;
#pragma unroll
            for (int j = 0; j < 4; ++j) {
                const int col = n0 + wn + j * 16 + l15;
#pragma unroll
                for (int r = 0; r < 4; ++r)
                    Cp[(size_t)(row + r) * N + col] = f2bf_rne(acc[i][j][r]);
            }
        }
    } else {
#pragma unroll
        for (int i = 0; i < 2; ++i) {
            const int row = m0 + wm + i * 16 + quad * 4;
#pragma unroll
            for (int j = 0; j < 4; ++j) {
                const int col = n0 + wn + j * 16 + l15;
                const float bv = HAS_BIAS ? bias[col] : 0.f;
#pragma unroll
                for (int r = 0; r < 4; ++r) {
                    float v = acc[i][j][r] + bv;
                    if (RELU) v = fmaxf(v, 0.f);
                    if (OUT_BF16)
                        ((ushort_t*)Cout)[(size_t)(row + r) * N + col] = f2bf_rne(v);
                    else
                        ((float*)Cout)[(size_t)(row + r) * N + col] = v;
                }
            }
        }
    }
}

// plain gemm launch (whole grid is gemm blocks)
template <bool RELU, bool OUT_BF16, bool HAS_BIAS, bool PARTIAL, bool FUSE_ATT>
__global__ __launch_bounds__(256) void gemm_tile(
    const ushort_t* __restrict__ A, const ushort_t* __restrict__ W,
    const float* __restrict__ bias, void* __restrict__ Cout,
    const float* __restrict__ lpart,
    int M, int N, int K, int Ksplit, int nx)
{
    gemm_body<RELU, OUT_BF16, HAS_BIAS, PARTIAL, FUSE_ATT>(
        blockIdx.x, gridDim.x, A, W, bias, Cout, lpart, M, N, K, Ksplit, nx);
}

// ---------------------------------------------------------------------------
// QKV gemm + shadow-batched codes packing.
// blocks [0, QKV_G): gemm; [QKV_G, QKV_G + 2048): rel/mask -> codes.
// ---------------------------------------------------------------------------
#define QKV_G (3 * DD / 128 * 32)   // 576

__global__ __launch_bounds__(256) void qkv_codes_kernel(
    const ushort_t* __restrict__ A, const ushort_t* __restrict__ W,
    ushort_t* __restrict__ Cout,
    const int* __restrict__ rel, const uchar_t* __restrict__ mask,
    unsigned* __restrict__ codes)
{
    const int bx = blockIdx.x;
    if (bx < QKV_G) {
        gemm_body<false, true, false, false, false>(
            bx, QKV_G, A, W, nullptr, Cout, nullptr,
            BS2, 3 * DD, DD, DD, 3 * DD / 128);
        return;
    }
    const int t = threadIdx.x;
    int tid = (bx - QKV_G) * 256 + t;
    int l15 = tid & 15;
    int kt  = (tid >> 4) & 15;
    int q   = (tid >> 8) & (SS - 1);
    int bb  = tid >> 18;
    const int* rrow = rel + ((size_t)(bb * SS + q)) * SS + kt * 64 + l15;
    const uchar_t* mrow = mask + (size_t)bb * SS + kt * 64 + l15;
    unsigned o = 0;
#pragma unroll
    for (int nt = 0; nt < 4; ++nt) {
        unsigned c = mrow[nt * 16] ? 3u : (unsigned)(rrow[nt * 16] + 1);
        o |= c << (8 * nt);
    }
    codes[((size_t)(bb * SS + q) * 16 + kt) * 16 + l15] = o;
}

// ---------------------------------------------------------------------------
// MFMA flash attention (R11: R10 core + SINGLE-BUFFER V -> LDS 44->35 KB ->
// 4 blocks/CU instead of 3. Correctness: end-of-iter barrier PAIR
// {sync; write Vt(next); sync} replaces {write Vt2[nb]; sync}.
// K stays double-buffered (global_load_lds prefetch), codes stay
// register-double-buffered (R10)) + shadow-batched o_w/w1/w2 conversion.
// ---------------------------------------------------------------------------
#define ATT_G (BB * HH * 16 * 2)        // 768
#define RC1 (DD * DD / 4)
#define RC2 (RC1 + DFF * DD / 4)
#define RCT (RC2 + DD * DFF / 4)
#define RCVT_BLK (RCT / 256)            // 5184

__global__ __launch_bounds__(256) void attn_cvt_kernel(
    const ushort_t* __restrict__ qkv,
    const unsigned* __restrict__ codes,
    const float* __restrict__ rel_A,
    ushort_t* __restrict__ Opart,
    float* __restrict__ lpart,
    const float* __restrict__ o_w, const float* __restrict__ w1,
    const float* __restrict__ w2, ushort_t* __restrict__ wrest)
{
    const int bx = blockIdx.x;
    const int t  = threadIdx.x;
    if (bx >= ATT_G) {
        int i = (bx - ATT_G) * 256 + t;
        const float* src; int off;
        if (i < RC1)      { src = o_w; off = i; }
        else if (i < RC2) { src = w1;  off = i - RC1; }
        else              { src = w2;  off = i - RC2; }
        cvt_quad(src, off, wrest, i);
        return;
    }

    __shared__ __align__(16) ushort_t Ks[2][64 * 64];   // 16 KB (dbuf, DMA)
    __shared__ __align__(16) unsigned Vt[64 * 36];      // 9 KB  (SINGLE buf)
    __shared__ __align__(16) ushort_t Ps[64 * 72];      // 9 KB
    __shared__ __align__(16) float r3s[64][4];          // 1 KB   => 35 KB tot

    const int ks = bx & 1;
    const int qt = (bx >> 1) & 15;
    const int h  = (bx >> 5) % HH;
    const int b  = bx / (32 * HH);
    const int q0 = qt * 64;
    const int w  = t >> 6;
    const int l  = t & 63;
    const int l15  = l & 15;
    const int quad = l >> 4;

    const int sr  = t >> 3;
    const int scp = t & 7;
    const int vkp = t >> 3;
    const int vdg = t & 7;
    const int vkps = vkp ^ (vdg * 4);

    const int kt0 = ks * 8;

    const size_t qrow = (size_t)(b * SS + q0 + w * 16 + l15) * (3 * DD) + h * HD;
    const short8 qf0 = *(const short8*)(qkv + qrow + quad * 8);
    const short8 qf1 = *(const short8*)(qkv + qrow + 32 + quad * 8);

    // codes base for this thread: index (qloc,kt) -> cb[qloc*256 + (kt-kt0)*16]
    const unsigned* cb = codes + ((size_t)(b * SS + q0) * 16 + kt0) * 16 + l15;
    unsigned ccur[4], cnxt[4];
#pragma unroll
    for (int reg = 0; reg < 4; ++reg) {
        const int qloc = w * 16 + quad * 4 + reg;
        ccur[reg] = cb[(size_t)qloc * 256];          // iter 0's codes, issued early
    }

    {
        float rv[3];
#pragma unroll
        for (int c = 0; c < 3; ++c) {
            const float* a = rel_A + c * HD + quad * 8;
            float acc = 0.f;
#pragma unroll
            for (int j = 0; j < 8; ++j) acc += bf2f(qf0[j]) * a[j];
#pragma unroll
            for (int j = 0; j < 8; ++j) acc += bf2f(qf1[j]) * a[32 + j];
            acc += __shfl_xor(acc, 16);
            acc += __shfl_xor(acc, 32);
            rv[c] = acc;
        }
        if (quad == 0) {
            float4 f4 = make_float4(rv[0], rv[1], rv[2], -2.4e31f);
            *(float4*)&r3s[w * 16 + l15][0] = f4;
        }
    }

    float l_run[4] = {0.f, 0.f, 0.f, 0.f};
    f32x4 oacc[4] = {};

    short8 va, vb;
    {
        const int k0 = kt0 * 64;
        const int cl  = scp ^ (sr & 7);
        const ushort_t* g = qkv + (size_t)(b * SS + k0 + sr) * (3 * DD) + DD + h * HD + cl * 8;
        __builtin_amdgcn_global_load_lds(
            (const __attribute__((address_space(1))) unsigned*)g,
            (__attribute__((address_space(3))) unsigned*)(&Ks[0][0] + (size_t)t * 8), 16, 0, 0);
        const int r2  = sr + 32;
        const int cl2 = scp ^ (r2 & 7);
        const ushort_t* g2 = qkv + (size_t)(b * SS + k0 + r2) * (3 * DD) + DD + h * HD + cl2 * 8;
        __builtin_amdgcn_global_load_lds(
            (const __attribute__((address_space(1))) unsigned*)g2,
            (__attribute__((address_space(3))) unsigned*)(&Ks[0][0] + (size_t)(t + 256) * 8), 16, 0, 0);
        const ushort_t* gv = qkv + (size_t)(b * SS + k0 + 2 * vkp) * (3 * DD) + 2 * DD + h * HD + vdg * 8;
        va = *(const short8*)gv;
        vb = *(const short8*)(gv + 3 * DD);
#pragma unroll
        for (int i = 0; i < 8; ++i)
            Vt[(size_t)(vdg * 8 + i) * 36 + vkps] =
                (unsigned)(ushort_t)va[i] | ((unsigned)(ushort_t)vb[i] << 16);
    }
    __syncthreads();
    float4 r3v[4];
#pragma unroll
    for (int reg = 0; reg < 4; ++reg)
        r3v[reg] = *(const float4*)&r3s[w * 16 + quad * 4 + reg][0];

    for (int i8 = 0; i8 < 8; ++i8) {
        const int kt  = kt0 + i8;
        const int cur = i8 & 1;
        const bool more = (i8 + 1 < 8);
        if (more) {
            const int k0 = (kt + 1) * 64;
            const int nb = cur ^ 1;
            const int cl  = scp ^ (sr & 7);
            const ushort_t* g = qkv + (size_t)(b * SS + k0 + sr) * (3 * DD) + DD + h * HD + cl * 8;
            __builtin_amdgcn_global_load_lds(
                (const __attribute__((address_space(1))) unsigned*)g,
                (__attribute__((address_space(3))) unsigned*)(&Ks[nb][0] + (size_t)t * 8), 16, 0, 0);
            const int r2  = sr + 32;
            const int cl2 = scp ^ (r2 & 7);
            const ushort_t* g2 = qkv + (size_t)(b * SS + k0 + r2) * (3 * DD) + DD + h * HD + cl2 * 8;
            __builtin_amdgcn_global_load_lds(
                (const __attribute__((address_space(1))) unsigned*)g2,
                (__attribute__((address_space(3))) unsigned*)(&Ks[nb][0] + (size_t)(t + 256) * 8), 16, 0, 0);
            const ushort_t* gv = qkv + (size_t)(b * SS + k0 + 2 * vkp) * (3 * DD) + 2 * DD + h * HD + vdg * 8;
            va = *(const short8*)gv;
            vb = *(const short8*)(gv + 3 * DD);
            // prefetch next iteration's rel-codes (consumed next softmax phase)
#pragma unroll
            for (int reg = 0; reg < 4; ++reg) {
                const int qloc = w * 16 + quad * 4 + reg;
                cnxt[reg] = cb[(size_t)qloc * 256 + (size_t)(i8 + 1) * 16];
            }
        }

        f32x4 sacc[4] = {};
#pragma unroll
        for (int kc = 0; kc < 2; ++kc) {
            const short8 qv = kc ? qf1 : qf0;
#pragma unroll
            for (int nt = 0; nt < 4; ++nt) {
                const int row = nt * 16 + l15;
                const int cp  = (kc * 4 + quad) ^ (row & 7);
                const short8 kf = *(const short8*)(&Ks[cur][0] + (size_t)row * 64 + cp * 8);
                sacc[nt] = __builtin_amdgcn_mfma_f32_16x16x32_bf16(qv, kf, sacc[nt], 0, 0, 0);
            }
        }

#pragma unroll
        for (int reg = 0; reg < 4; ++reg) {
            const int qloc = w * 16 + quad * 4 + reg;
            const unsigned cds = ccur[reg];
            const float4 r4 = r3v[reg];
#pragma unroll
            for (int nt = 0; nt < 4; ++nt) {
                const unsigned c = (cds >> (8 * nt)) & 0xff;
                float rvv = (c == 0) ? r4.x : (c == 1) ? r4.y : (c == 2) ? r4.z : r4.w;
                const float p = __expf((sacc[nt][reg] + rvv) * 0.125f);
                l_run[reg] += p;
                Ps[(size_t)qloc * 72 + nt * 16 + l15] = f2bf_rne(p);
            }
        }

#pragma unroll
        for (int kc = 0; kc < 2; ++kc) {
            const short8 pf = *(const short8*)(Ps + (size_t)(w * 16 + l15) * 72 + kc * 32 + quad * 8);
#pragma unroll
            for (int dt = 0; dt < 4; ++dt) {
                const int d  = dt * 16 + l15;
                const int dg = d >> 3;
                const int kps0 = (kc * 16 + quad * 4) ^ ((dg & 7) * 4);
                const short8 vf = *(const short8*)((const ushort_t*)&Vt[(size_t)d * 36 + kps0]);
                oacc[dt] = __builtin_amdgcn_mfma_f32_16x16x32_bf16(pf, vf, oacc[dt], 0, 0, 0);
            }
        }

        if (more) {
            __syncthreads();   // all waves done reading Vt (current tile)
#pragma unroll
            for (int i = 0; i < 8; ++i)
                Vt[(size_t)(vdg * 8 + i) * 36 + vkps] =
                    (unsigned)(ushort_t)va[i] | ((unsigned)(ushort_t)vb[i] << 16);
#pragma unroll
            for (int reg = 0; reg < 4; ++reg)
                ccur[reg] = cnxt[reg];
            __syncthreads();   // next tile's Vt visible before next PV
        }
    }

    ushort_t* Op = Opart + (size_t)ks * BSD;
    float* lp = lpart + (size_t)ks * BS2 * HH;
#pragma unroll
    for (int reg = 0; reg < 4; ++reg) {
        float ls = l_run[reg];
        ls += __shfl_xor(ls, 1);
        ls += __shfl_xor(ls, 2);
        ls += __shfl_xor(ls, 4);
        ls += __shfl_xor(ls, 8);
        const int orow = b * SS + q0 + w * 16 + quad * 4 + reg;
#pragma unroll
        for (int dt = 0; dt < 4; ++dt)
            Op[(size_t)orow * DD + h * HD + dt * 16 + l15] = f2bf_rne(oacc[dt][reg]);
        if (l15 == 0) lp[(size_t)orow * HH + h] = ls;
    }
}

// ---------------------------------------------------------------------------
extern "C" void kernel_launch(void* const* d_in, const int* in_sizes, int n_in,
                              void* d_out, int out_size, void* d_ws, size_t ws_size,
                              hipStream_t stream) {
    const float* inp   = (const float*)d_in[0];
    const uchar_t* amask = (const uchar_t*)d_in[1];
    const int*   relm  = (const int*)d_in[2];
    const float* qkv_w = (const float*)d_in[3];
    const float* rel_A = (const float*)d_in[4];
    const float* o_w   = (const float*)d_in[5];
    const float* w1    = (const float*)d_in[6];
    const float* b1    = (const float*)d_in[7];
    const float* w2    = (const float*)d_in[8];
    const float* b2    = (const float*)d_in[9];
    const float* ln1_g = (const float*)d_in[10];
    const float* ln1_b = (const float*)d_in[11];
    const float* ln2_g = (const float*)d_in[12];
    const float* ln2_b = (const float*)d_in[13];
    float* out = (float*)d_out;

    // workspace layout (ow/w1/w2 bf16 MUST stay contiguous for shadow cvt)
    char* p = (char*)d_ws;
    ushort_t* x_bf   = (ushort_t*)p; p += BSD * 2;
    ushort_t* h_bf   = (ushort_t*)p; p += BSD * 2;
    ushort_t* ff_bf  = (ushort_t*)p; p += (size_t)BS2 * DFF * 2;
    ushort_t* qkvw_bf= (ushort_t*)p; p += (size_t)3 * DD * DD * 2;
    ushort_t* ow_bf  = (ushort_t*)p; p += (size_t)DD * DD * 2;
    ushort_t* w1_bf  = (ushort_t*)p; p += (size_t)DFF * DD * 2;
    ushort_t* w2_bf  = (ushort_t*)p; p += (size_t)DD * DFF * 2;
    ushort_t* qkv_bf = (ushort_t*)p; p += (size_t)BS2 * 3 * DD * 2;
    float*    resid  = (float*)p;    p += BSD * 4;
    ushort_t* pool   = (ushort_t*)p; p += 4 * BSD * 2;
    ushort_t* Opart  = (ushort_t*)p; p += 2 * BSD * 2;
    float*    lpart  = (float*)p;    p += (size_t)2 * BS2 * HH * 4;
    unsigned* codes  = (unsigned*)p; p += (size_t)BB * SS * SS;

    // 0. prep1: qkv_w cvt + LN1 only (critical-path minimum)
    prep1_kernel<<<P1_CVT + P1_LN, 256, 0, stream>>>(
        qkv_w, qkvw_bf, inp, ln1_g, ln1_b, x_bf);

    // 1. QKV gemm (576 blocks) + shadow codes packing (2048 blocks)
    qkv_codes_kernel<<<QKV_G + BB * SS, 256, 0, stream>>>(
        x_bf, qkvw_bf, qkv_bf, relm, amask, codes);

    // 2. attention (768) + shadow o_w/w1/w2 cvt (5184)
    attn_cvt_kernel<<<ATT_G + RCVT_BLK, 256, 0, stream>>>(
        qkv_bf, codes, rel_A, Opart, lpart, o_w, w1, w2, ow_bf);

    // 3. o-proj with FUSED attn merge, bf16 partials (Z=2) : 384 blocks
    gemm_tile<false, false, false, true, true>
        <<<DD / 128 * 32 * 2, 256, 0, stream>>>(
        Opart, ow_bf, nullptr, pool, lpart, BS2, DD, DD, DD / 2, DD / 128);

    // 4. fused: resid = inp + p0 + p1 ; h_bf = LN2(resid)
    merge2_ln_kernel<<<BS2, 256, 0, stream>>>(
        pool, inp, ln2_g, ln2_b, resid, h_bf);

    // 5. ff = relu(h @ w1.T + b1) -> bf16 : 24*32 = 768 blocks
    gemm_tile<true, true, true, false, false>
        <<<DFF / 128 * 32, 256, 0, stream>>>(
        h_bf, w1_bf, b1, ff_bf, nullptr, BS2, DFF, DD, DD, DFF / 128);

    // 6. MLP2 bf16 partials (Z=4) : 768 blocks
    gemm_tile<false, false, false, true, false>
        <<<DD / 128 * 32 * 4, 256, 0, stream>>>(
        ff_bf, w2_bf, nullptr, pool, nullptr, BS2, DD, DFF, DFF / 4, DD / 128);

    // 7. out = resid + b2 + p0..p3
    merge4_kernel<<<(int)(BSD / 4 / 256), 256, 0, stream>>>(
        pool, resid, b2, out, (int)(BSD / 4));
}

// Round 12
// 247.145 us; speedup vs baseline: 1.0108x; 1.0108x over previous
//
#include <hip/hip_runtime.h>
#include <hip/hip_bf16.h>

// Problem constants
#define BB 2
#define SS 1024
#define DD 768
#define HH 12
#define HD 64
#define DFF 3072
#define EPS 1e-5f
#define BS2 (BB * SS)            // 2048
#define BSD ((size_t)BS2 * DD)   // 2048*768

typedef unsigned short ushort_t;
typedef unsigned char uchar_t;
using short8 = __attribute__((ext_vector_type(8))) short;
using f32x4  = __attribute__((ext_vector_type(4))) float;

// s_waitcnt immediates (gfx9 encoding)
#define WAITCNT_LGKM0 0xC07F     // lgkmcnt(0), vmcnt/expcnt unconstrained

__device__ __forceinline__ ushort_t f2bf_rne(float f) {
    union { float f; unsigned u; } x; x.f = f;
    unsigned r = x.u + 0x7fff + ((x.u >> 16) & 1);
    return (ushort_t)(r >> 16);
}
__device__ __forceinline__ float bf2f(short u) {
    union { unsigned i; float f; } x;
    x.i = ((unsigned)(ushort_t)u) << 16;
    return x.f;
}
// (o0 + o1) * inv, elementwise bf16x8
__device__ __forceinline__ short8 mergeo(short8 a, short8 b, float inv) {
    short8 o;
#pragma unroll
    for (int i = 0; i < 8; ++i)
        o[i] = (short)f2bf_rne((bf2f(a[i]) + bf2f(b[i])) * inv);
    return o;
}

// fp32 -> bf16 cvt of one float4-quad per thread
__device__ __forceinline__ void cvt_quad(const float* __restrict__ src, int off,
                                         ushort_t* __restrict__ dst, int i) {
    float4 v = ((const float4*)src)[off];
    ushort4 o;
    o.x = f2bf_rne(v.x); o.y = f2bf_rne(v.y);
    o.z = f2bf_rne(v.z); o.w = f2bf_rne(v.w);
    ((ushort4*)dst)[i] = o;
}

// ---------------------------------------------------------------------------
// prep1: ONLY what QKV needs — qkv_w cvt (1728 blocks) + LN1 (2048 blocks).
// ---------------------------------------------------------------------------
#define P1_CVT (3 * DD * DD / 4 / 256)   // 1728
#define P1_LN  BS2                        // 2048

__global__ __launch_bounds__(256) void prep1_kernel(
    const float* __restrict__ qkv_w, ushort_t* __restrict__ qkvw_bf,
    const float* __restrict__ x, const float* __restrict__ g,
    const float* __restrict__ b, ushort_t* __restrict__ y)
{
    const int bx = blockIdx.x;
    const int t  = threadIdx.x;
    if (bx < P1_CVT) {
        int i = bx * 256 + t;
        cvt_quad(qkv_w, i, qkvw_bf, i);
        return;
    }
    // ---- LN1 ----
    const int row = bx - P1_CVT;
    const float* xr = x + (size_t)row * DD;
    float s = 0.f, ss = 0.f;
    for (int i = t; i < DD; i += 256) {
        float v = xr[i];
        s += v; ss += v * v;
    }
    for (int off = 32; off; off >>= 1) {
        s  += __shfl_down(s,  off);
        ss += __shfl_down(ss, off);
    }
    __shared__ float reds[4], redss[4], bc[2];
    if ((t & 63) == 0) { reds[t >> 6] = s; redss[t >> 6] = ss; }
    __syncthreads();
    if (t == 0) {
        float S1 = reds[0] + reds[1] + reds[2] + reds[3];
        float S2 = redss[0] + redss[1] + redss[2] + redss[3];
        float mean = S1 / DD;
        float var = S2 / DD - mean * mean;
        bc[0] = mean;
        bc[1] = rsqrtf(var + EPS);
    }
    __syncthreads();
    float mean = bc[0], inv = bc[1];
    ushort_t* yr = y + (size_t)row * DD;
    for (int i = t; i < DD; i += 256) {
        yr[i] = f2bf_rne((xr[i] - mean) * inv * g[i] + b[i]);
    }
}

// ---------------------------------------------------------------------------
// Fused: resid = inp + p0 + p1 (bf16 partials) ; h_bf = LN(resid).
// ---------------------------------------------------------------------------
__global__ __launch_bounds__(256) void merge2_ln_kernel(
    const ushort_t* __restrict__ part, const float* __restrict__ inp,
    const float* __restrict__ g, const float* __restrict__ b,
    float* __restrict__ resid, ushort_t* __restrict__ h_bf)
{
    const int row = blockIdx.x;
    const int t = threadIdx.x;
    float4 v = make_float4(0.f, 0.f, 0.f, 0.f);
    const size_t idx = (size_t)row * (DD / 4) + t;
    if (t < DD / 4) {
        v = ((const float4*)inp)[idx];
        ushort4 p0 = ((const ushort4*)part)[idx];
        ushort4 p1 = ((const ushort4*)(part + BSD))[idx];
        v.x += bf2f(p0.x) + bf2f(p1.x);
        v.y += bf2f(p0.y) + bf2f(p1.y);
        v.z += bf2f(p0.z) + bf2f(p1.z);
        v.w += bf2f(p0.w) + bf2f(p1.w);
        ((float4*)resid)[idx] = v;
    }
    float s  = v.x + v.y + v.z + v.w;
    float ss = v.x * v.x + v.y * v.y + v.z * v.z + v.w * v.w;
    for (int off = 32; off; off >>= 1) {
        s  += __shfl_down(s,  off);
        ss += __shfl_down(ss, off);
    }
    __shared__ float reds[4], redss[4], bc[2];
    if ((t & 63) == 0) { reds[t >> 6] = s; redss[t >> 6] = ss; }
    __syncthreads();
    if (t == 0) {
        float S1 = reds[0] + reds[1] + reds[2] + reds[3];
        float S2 = redss[0] + redss[1] + redss[2] + redss[3];
        float mean = S1 / DD;
        float var = S2 / DD - mean * mean;
        bc[0] = mean;
        bc[1] = rsqrtf(var + EPS);
    }
    __syncthreads();
    if (t < DD / 4) {
        const float mean = bc[0], inv = bc[1];
        float4 gv = ((const float4*)g)[t];
        float4 bv = ((const float4*)b)[t];
        ushort4 o;
        o.x = f2bf_rne((v.x - mean) * inv * gv.x + bv.x);
        o.y = f2bf_rne((v.y - mean) * inv * gv.y + bv.y);
        o.z = f2bf_rne((v.z - mean) * inv * gv.z + bv.z);
        o.w = f2bf_rne((v.w - mean) * inv * gv.w + bv.w);
        ((ushort4*)h_bf)[idx] = o;
    }
}

// ---------------------------------------------------------------------------
// merge4: out = resid + b2 + sum of 4 bf16 partial slices.
// ---------------------------------------------------------------------------
__global__ __launch_bounds__(256) void merge4_kernel(
    const ushort_t* __restrict__ part, const float* __restrict__ resid,
    const float* __restrict__ b2, float* __restrict__ outp, int n4)
{
    int i = blockIdx.x * 256 + threadIdx.x;
    if (i >= n4) return;
    float4 v = ((const float4*)resid)[i];
    int col4 = (i * 4) % DD;
    float4 bv = *(const float4*)(b2 + col4);
    v.x += bv.x; v.y += bv.y; v.z += bv.z; v.w += bv.w;
#pragma unroll
    for (int z = 0; z < 4; ++z) {
        ushort4 pz = ((const ushort4*)(part + (size_t)z * BSD))[i];
        v.x += bf2f(pz.x); v.y += bf2f(pz.y);
        v.z += bf2f(pz.z); v.w += bf2f(pz.w);
    }
    ((float4*)outp)[i] = v;
}

// ---------------------------------------------------------------------------
// REGISTER-PIPELINED MFMA GEMM BODY (R3 core — best measured), 64x128 tile,
// BK=64, 256 threads = 4 waves, XCD-chunked swizzle with explicit gemm-block
// count `nwg` (the launch may carry extra shadow blocks after the gemm range).
// FUSE_ATT: A is the attention k-split pair merged on the fly (R5/R7 path).
// ---------------------------------------------------------------------------
template <bool RELU, bool OUT_BF16, bool HAS_BIAS, bool PARTIAL, bool FUSE_ATT>
__device__ __forceinline__ void gemm_body(
    int bid, int nwg,
    const ushort_t* __restrict__ A, const ushort_t* __restrict__ W,
    const float* __restrict__ bias, void* __restrict__ Cout,
    const float* __restrict__ lpart,
    int M, int N, int K, int Ksplit, int nx)
{
    __shared__ __align__(16) ushort_t As[512 * 8];    // 8 KB  (64 rows x 8 kq)
    __shared__ __align__(16) ushort_t Bs[1024 * 8];   // 16 KB (128 rows x 8 kq)

    // XCD-chunked decode: nwg % 8 == 0 for all our launches.
    const int swz = (bid & 7) * (nwg >> 3) + (bid >> 3);
    const int by  = swz & 31;          // ny = 32 always (M=2048, 64-row tiles)
    const int t2  = swz >> 5;
    const int bxx = t2 % nx;
    const int bz  = t2 / nx;

    const int t  = threadIdx.x;
    const int n0 = bxx * 128;
    const int m0 = by * 64;
    const int kb = bz * Ksplit;
    const int w  = t >> 6;
    const int l  = t & 63;
    const int wm = (w & 1) * 32;
    const int wn = (w >> 1) * 64;
    const int l15  = l & 15;
    const int quad = l >> 4;

    const ushort_t* gA = A + (size_t)(m0 + (t & 63)) * K + kb + (t >> 6) * 8;
    const ushort_t* gB = W + (size_t)(n0 + (t & 127)) * K + kb + (t >> 7) * 8;

    const float* lp0 = nullptr; const float* lp1 = nullptr;
    const int hbase = kb >> 6;
    if (FUSE_ATT) {
        lp0 = lpart + (size_t)(m0 + (t & 63)) * HH;
        lp1 = lp0 + (size_t)BS2 * HH;
    }

    // prologue: stage tile 0 into registers
    short8 pa0, pa1, ra0, ra1, sa0, sa1;
    float li0 = 0.f, li1 = 0.f;
    if (FUSE_ATT) {
        ra0 = *(const short8*)(gA);
        ra1 = *(const short8*)(gA + 32);
        sa0 = *(const short8*)(gA + BSD);
        sa1 = *(const short8*)(gA + BSD + 32);
        li0 = lp0[hbase];
        li1 = lp1[hbase];
    } else {
        pa0 = *(const short8*)(gA);
        pa1 = *(const short8*)(gA + 32);
    }
    short8 pb0 = *(const short8*)(gB);
    short8 pb1 = *(const short8*)(gB + 16);
    short8 pb2 = *(const short8*)(gB + 32);
    short8 pb3 = *(const short8*)(gB + 48);

    f32x4 acc[2][4] = {};
    const int nIter = Ksplit >> 6;

    for (int it = 0; it < nIter; ++it) {
        // barrier A: all waves finished reading LDS from the previous iter
        __builtin_amdgcn_s_barrier();
        if (FUSE_ATT) {
            const float inv = 1.0f / (li0 + li1);
            pa0 = mergeo(ra0, sa0, inv);
            pa1 = mergeo(ra1, sa1, inv);
        }
        // commit staged tile to LDS (compiler inserts precise vmcnt waits)
        *(short8*)&As[(size_t)t * 8]           = pa0;
        *(short8*)&As[(size_t)(t + 256) * 8]   = pa1;
        *(short8*)&Bs[(size_t)t * 8]           = pb0;
        *(short8*)&Bs[(size_t)(t + 256) * 8]   = pb1;
        *(short8*)&Bs[(size_t)(t + 512) * 8]   = pb2;
        *(short8*)&Bs[(size_t)(t + 768) * 8]   = pb3;
        // issue next tile's loads (in flight across the whole compute phase)
        if (it + 1 < nIter) {
            const int k0 = (it + 1) << 6;
            if (FUSE_ATT) {
                ra0 = *(const short8*)(gA + k0);
                ra1 = *(const short8*)(gA + k0 + 32);
                sa0 = *(const short8*)(gA + k0 + BSD);
                sa1 = *(const short8*)(gA + k0 + BSD + 32);
                li0 = lp0[hbase + it + 1];
                li1 = lp1[hbase + it + 1];
            } else {
                pa0 = *(const short8*)(gA + k0);
                pa1 = *(const short8*)(gA + k0 + 32);
            }
            pb0 = *(const short8*)(gB + k0);
            pb1 = *(const short8*)(gB + k0 + 16);
            pb2 = *(const short8*)(gB + k0 + 32);
            pb3 = *(const short8*)(gB + k0 + 48);
        }
        // my ds_writes done; barrier B: everyone's writes visible
        __builtin_amdgcn_s_waitcnt(WAITCNT_LGKM0);
        __builtin_amdgcn_s_barrier();

#pragma unroll
        for (int ks = 0; ks < 2; ++ks) {
            const ushort_t* aptr = &As[(size_t)((ks * 4 + quad) * 64 + wm + l15) * 8];
            const ushort_t* bptr = &Bs[(size_t)((ks * 4 + quad) * 128 + wn + l15) * 8];
            short8 af[2], bf[4];
#pragma unroll
            for (int i = 0; i < 2; ++i)
                af[i] = *(const short8*)(aptr + (size_t)i * 16 * 8);
#pragma unroll
            for (int j = 0; j < 4; ++j)
                bf[j] = *(const short8*)(bptr + (size_t)j * 16 * 8);
#pragma unroll
            for (int i = 0; i < 2; ++i)
#pragma unroll
                for (int j = 0; j < 4; ++j)
                    acc[i][j] = __builtin_amdgcn_mfma_f32_16x16x32_bf16(
                        af[i], bf[j], acc[i][j], 0, 0, 0);
        }
    }

    // epilogue: C/D layout col=lane&15, row=(lane>>4)*4+reg
    if (PARTIAL) {
        ushort_t* Cp = (ushort_t*)Cout + (size_t)bz * ((size_t)M * N);
#pragma unroll
        for (int i = 0; i < 2; ++i) {
            const int row = m0 + wm + i * 16 + quad * 4;
#pragma unroll
            for (int j = 0; j < 4; ++j) {
                const int col = n0 + wn + j * 16 + l15;
#pragma unroll
                for (int r = 0; r < 4; ++r)
                    Cp[(size_t)(row + r) * N + col] = f2bf_rne(acc[i][j][r]);
            }
        }
    } else {
#pragma unroll
        for (int i = 0; i < 2; ++i) {
            const int row = m0 + wm + i * 16 + quad * 4;
#pragma unroll
            for (int j = 0; j < 4; ++j) {
                const int col = n0 + wn + j * 16 + l15;
                const float bv = HAS_BIAS ? bias[col] : 0.f;
#pragma unroll
                for (int r = 0; r < 4; ++r) {
                    float v = acc[i][j][r] + bv;
                    if (RELU) v = fmaxf(v, 0.f);
                    if (OUT_BF16)
                        ((ushort_t*)Cout)[(size_t)(row + r) * N + col] = f2bf_rne(v);
                    else
                        ((float*)Cout)[(size_t)(row + r) * N + col] = v;
                }
            }
        }
    }
}

// plain gemm launch (whole grid is gemm blocks)
template <bool RELU, bool OUT_BF16, bool HAS_BIAS, bool PARTIAL, bool FUSE_ATT>
__global__ __launch_bounds__(256) void gemm_tile(
    const ushort_t* __restrict__ A, const ushort_t* __restrict__ W,
    const float* __restrict__ bias, void* __restrict__ Cout,
    const float* __restrict__ lpart,
    int M, int N, int K, int Ksplit, int nx)
{
    gemm_body<RELU, OUT_BF16, HAS_BIAS, PARTIAL, FUSE_ATT>(
        blockIdx.x, gridDim.x, A, W, bias, Cout, lpart, M, N, K, Ksplit, nx);
}

// ---------------------------------------------------------------------------
// QKV gemm + shadow-batched codes packing.
// blocks [0, QKV_G): gemm; [QKV_G, QKV_G + 2048): rel/mask -> codes.
// ---------------------------------------------------------------------------
#define QKV_G (3 * DD / 128 * 32)   // 576

__global__ __launch_bounds__(256) void qkv_codes_kernel(
    const ushort_t* __restrict__ A, const ushort_t* __restrict__ W,
    ushort_t* __restrict__ Cout,
    const int* __restrict__ rel, const uchar_t* __restrict__ mask,
    unsigned* __restrict__ codes)
{
    const int bx = blockIdx.x;
    if (bx < QKV_G) {
        gemm_body<false, true, false, false, false>(
            bx, QKV_G, A, W, nullptr, Cout, nullptr,
            BS2, 3 * DD, DD, DD, 3 * DD / 128);
        return;
    }
    const int t = threadIdx.x;
    int tid = (bx - QKV_G) * 256 + t;
    int l15 = tid & 15;
    int kt  = (tid >> 4) & 15;
    int q   = (tid >> 8) & (SS - 1);
    int bb  = tid >> 18;
    const int* rrow = rel + ((size_t)(bb * SS + q)) * SS + kt * 64 + l15;
    const uchar_t* mrow = mask + (size_t)bb * SS + kt * 64 + l15;
    unsigned o = 0;
#pragma unroll
    for (int nt = 0; nt < 4; ++nt) {
        unsigned c = mrow[nt * 16] ? 3u : (unsigned)(rrow[nt * 16] + 1);
        o |= c << (8 * nt);
    }
    codes[((size_t)(bb * SS + q) * 16 + kt) * 16 + l15] = o;
}

// ---------------------------------------------------------------------------
// o-proj (FUSE_ATT, 384 gemm blocks) + shadow w1 cvt (2304 blocks).
// oproj LDS 24KB -> 6 blocks/CU capacity (1536): all gemm blocks resident in
// the first dispatch wave; w1-cvt blocks fill otherwise-idle slots.
// ---------------------------------------------------------------------------
#define OPJ_G (DD / 128 * 32 * 2)        // 384
#define W1_BLK (DFF * DD / 4 / 256)      // 2304

__global__ __launch_bounds__(256) void oproj_w1_kernel(
    const ushort_t* __restrict__ A, const ushort_t* __restrict__ W,
    void* __restrict__ Cout, const float* __restrict__ lpart,
    const float* __restrict__ w1, ushort_t* __restrict__ w1_bf)
{
    const int bx = blockIdx.x;
    if (bx < OPJ_G) {
        gemm_body<false, false, false, true, true>(
            bx, OPJ_G, A, W, nullptr, Cout, lpart,
            BS2, DD, DD, DD / 2, DD / 128);
        return;
    }
    int i = (bx - OPJ_G) * 256 + threadIdx.x;
    cvt_quad(w1, i, w1_bf, i);
}

// ---------------------------------------------------------------------------
// MLP1 (relu gemm, 768 blocks) + shadow w2 cvt (2304 blocks).
// ---------------------------------------------------------------------------
#define M1_G (DFF / 128 * 32)            // 768
#define W2_BLK (DD * DFF / 4 / 256)      // 2304

__global__ __launch_bounds__(256) void mlp1_w2_kernel(
    const ushort_t* __restrict__ A, const ushort_t* __restrict__ W,
    const float* __restrict__ bias, void* __restrict__ Cout,
    const float* __restrict__ w2, ushort_t* __restrict__ w2_bf)
{
    const int bx = blockIdx.x;
    if (bx < M1_G) {
        gemm_body<true, true, true, false, false>(
            bx, M1_G, A, W, bias, Cout, nullptr,
            BS2, DFF, DD, DD, DFF / 128);
        return;
    }
    int i = (bx - M1_G) * 256 + threadIdx.x;
    cvt_quad(w2, i, w2_bf, i);
}

// ---------------------------------------------------------------------------
// MFMA flash attention (R10 core: K dbuf via global_load_lds, V dbuf in LDS,
// rel-codes register double-buffered) + shadow o_w cvt ONLY (576 blocks —
// w1/w2 cvt moved to the o-proj / MLP1 launches where they hide instead of
// tailing behind attention's 3-blocks/CU LDS limit).
// ---------------------------------------------------------------------------
#define ATT_G (BB * HH * 16 * 2)        // 768
#define OW_BLK (DD * DD / 4 / 256)      // 576

__global__ __launch_bounds__(256) void attn_cvt_kernel(
    const ushort_t* __restrict__ qkv,
    const unsigned* __restrict__ codes,
    const float* __restrict__ rel_A,
    ushort_t* __restrict__ Opart,
    float* __restrict__ lpart,
    const float* __restrict__ o_w, ushort_t* __restrict__ ow_bf)
{
    const int bx = blockIdx.x;
    const int t  = threadIdx.x;
    if (bx >= ATT_G) {
        int i = (bx - ATT_G) * 256 + t;
        cvt_quad(o_w, i, ow_bf, i);
        return;
    }

    __shared__ __align__(16) ushort_t Ks[2][64 * 64];
    __shared__ __align__(16) unsigned Vt2[2][64 * 36];
    __shared__ __align__(16) ushort_t Ps[64 * 72];
    __shared__ __align__(16) float r3s[64][4];

    const int ks = bx & 1;
    const int qt = (bx >> 1) & 15;
    const int h  = (bx >> 5) % HH;
    const int b  = bx / (32 * HH);
    const int q0 = qt * 64;
    const int w  = t >> 6;
    const int l  = t & 63;
    const int l15  = l & 15;
    const int quad = l >> 4;

    const int sr  = t >> 3;
    const int scp = t & 7;
    const int vkp = t >> 3;
    const int vdg = t & 7;
    const int vkps = vkp ^ (vdg * 4);

    const int kt0 = ks * 8;

    const size_t qrow = (size_t)(b * SS + q0 + w * 16 + l15) * (3 * DD) + h * HD;
    const short8 qf0 = *(const short8*)(qkv + qrow + quad * 8);
    const short8 qf1 = *(const short8*)(qkv + qrow + 32 + quad * 8);

    // codes base for this thread: index (qloc,kt) -> cb[qloc*256 + (kt-kt0)*16]
    const unsigned* cb = codes + ((size_t)(b * SS + q0) * 16 + kt0) * 16 + l15;
    unsigned ccur[4], cnxt[4];
#pragma unroll
    for (int reg = 0; reg < 4; ++reg) {
        const int qloc = w * 16 + quad * 4 + reg;
        ccur[reg] = cb[(size_t)qloc * 256];          // iter 0's codes, issued early
    }

    {
        float rv[3];
#pragma unroll
        for (int c = 0; c < 3; ++c) {
            const float* a = rel_A + c * HD + quad * 8;
            float acc = 0.f;
#pragma unroll
            for (int j = 0; j < 8; ++j) acc += bf2f(qf0[j]) * a[j];
#pragma unroll
            for (int j = 0; j < 8; ++j) acc += bf2f(qf1[j]) * a[32 + j];
            acc += __shfl_xor(acc, 16);
            acc += __shfl_xor(acc, 32);
            rv[c] = acc;
        }
        if (quad == 0) {
            float4 f4 = make_float4(rv[0], rv[1], rv[2], -2.4e31f);
            *(float4*)&r3s[w * 16 + l15][0] = f4;
        }
    }

    float l_run[4] = {0.f, 0.f, 0.f, 0.f};
    f32x4 oacc[4] = {};

    short8 va, vb;
    {
        const int k0 = kt0 * 64;
        const int cl  = scp ^ (sr & 7);
        const ushort_t* g = qkv + (size_t)(b * SS + k0 + sr) * (3 * DD) + DD + h * HD + cl * 8;
        __builtin_amdgcn_global_load_lds(
            (const __attribute__((address_space(1))) unsigned*)g,
            (__attribute__((address_space(3))) unsigned*)(&Ks[0][0] + (size_t)t * 8), 16, 0, 0);
        const int r2  = sr + 32;
        const int cl2 = scp ^ (r2 & 7);
        const ushort_t* g2 = qkv + (size_t)(b * SS + k0 + r2) * (3 * DD) + DD + h * HD + cl2 * 8;
        __builtin_amdgcn_global_load_lds(
            (const __attribute__((address_space(1))) unsigned*)g2,
            (__attribute__((address_space(3))) unsigned*)(&Ks[0][0] + (size_t)(t + 256) * 8), 16, 0, 0);
        const ushort_t* gv = qkv + (size_t)(b * SS + k0 + 2 * vkp) * (3 * DD) + 2 * DD + h * HD + vdg * 8;
        va = *(const short8*)gv;
        vb = *(const short8*)(gv + 3 * DD);
#pragma unroll
        for (int i = 0; i < 8; ++i)
            Vt2[0][(size_t)(vdg * 8 + i) * 36 + vkps] =
                (unsigned)(ushort_t)va[i] | ((unsigned)(ushort_t)vb[i] << 16);
    }
    __syncthreads();
    float4 r3v[4];
#pragma unroll
    for (int reg = 0; reg < 4; ++reg)
        r3v[reg] = *(const float4*)&r3s[w * 16 + quad * 4 + reg][0];

    for (int i8 = 0; i8 < 8; ++i8) {
        const int kt  = kt0 + i8;
        const int cur = i8 & 1;
        const bool more = (i8 + 1 < 8);
        if (more) {
            const int k0 = (kt + 1) * 64;
            const int nb = cur ^ 1;
            const int cl  = scp ^ (sr & 7);
            const ushort_t* g = qkv + (size_t)(b * SS + k0 + sr) * (3 * DD) + DD + h * HD + cl * 8;
            __builtin_amdgcn_global_load_lds(
                (const __attribute__((address_space(1))) unsigned*)g,
                (__attribute__((address_space(3))) unsigned*)(&Ks[nb][0] + (size_t)t * 8), 16, 0, 0);
            const int r2  = sr + 32;
            const int cl2 = scp ^ (r2 & 7);
            const ushort_t* g2 = qkv + (size_t)(b * SS + k0 + r2) * (3 * DD) + DD + h * HD + cl2 * 8;
            __builtin_amdgcn_global_load_lds(
                (const __attribute__((address_space(1))) unsigned*)g2,
                (__attribute__((address_space(3))) unsigned*)(&Ks[nb][0] + (size_t)(t + 256) * 8), 16, 0, 0);
            const ushort_t* gv = qkv + (size_t)(b * SS + k0 + 2 * vkp) * (3 * DD) + 2 * DD + h * HD + vdg * 8;
            va = *(const short8*)gv;
            vb = *(const short8*)(gv + 3 * DD);
            // prefetch next iteration's rel-codes (consumed next softmax phase)
#pragma unroll
            for (int reg = 0; reg < 4; ++reg) {
                const int qloc = w * 16 + quad * 4 + reg;
                cnxt[reg] = cb[(size_t)qloc * 256 + (size_t)(i8 + 1) * 16];
            }
        }

        f32x4 sacc[4] = {};
#pragma unroll
        for (int kc = 0; kc < 2; ++kc) {
            const short8 qv = kc ? qf1 : qf0;
#pragma unroll
            for (int nt = 0; nt < 4; ++nt) {
                const int row = nt * 16 + l15;
                const int cp  = (kc * 4 + quad) ^ (row & 7);
                const short8 kf = *(const short8*)(&Ks[cur][0] + (size_t)row * 64 + cp * 8);
                sacc[nt] = __builtin_amdgcn_mfma_f32_16x16x32_bf16(qv, kf, sacc[nt], 0, 0, 0);
            }
        }

#pragma unroll
        for (int reg = 0; reg < 4; ++reg) {
            const int qloc = w * 16 + quad * 4 + reg;
            const unsigned cds = ccur[reg];
            const float4 r4 = r3v[reg];
#pragma unroll
            for (int nt = 0; nt < 4; ++nt) {
                const unsigned c = (cds >> (8 * nt)) & 0xff;
                float rvv = (c == 0) ? r4.x : (c == 1) ? r4.y : (c == 2) ? r4.z : r4.w;
                const float p = __expf((sacc[nt][reg] + rvv) * 0.125f);
                l_run[reg] += p;
                Ps[(size_t)qloc * 72 + nt * 16 + l15] = f2bf_rne(p);
            }
        }

#pragma unroll
        for (int kc = 0; kc < 2; ++kc) {
            const short8 pf = *(const short8*)(Ps + (size_t)(w * 16 + l15) * 72 + kc * 32 + quad * 8);
#pragma unroll
            for (int dt = 0; dt < 4; ++dt) {
                const int d  = dt * 16 + l15;
                const int dg = d >> 3;
                const int kps0 = (kc * 16 + quad * 4) ^ ((dg & 7) * 4);
                const short8 vf = *(const short8*)((const ushort_t*)&Vt2[cur][(size_t)d * 36 + kps0]);
                oacc[dt] = __builtin_amdgcn_mfma_f32_16x16x32_bf16(pf, vf, oacc[dt], 0, 0, 0);
            }
        }

        if (more) {
            const int nb = cur ^ 1;
#pragma unroll
            for (int i = 0; i < 8; ++i)
                Vt2[nb][(size_t)(vdg * 8 + i) * 36 + vkps] =
                    (unsigned)(ushort_t)va[i] | ((unsigned)(ushort_t)vb[i] << 16);
#pragma unroll
            for (int reg = 0; reg < 4; ++reg)
                ccur[reg] = cnxt[reg];
            __syncthreads();
        }
    }

    ushort_t* Op = Opart + (size_t)ks * BSD;
    float* lp = lpart + (size_t)ks * BS2 * HH;
#pragma unroll
    for (int reg = 0; reg < 4; ++reg) {
        float ls = l_run[reg];
        ls += __shfl_xor(ls, 1);
        ls += __shfl_xor(ls, 2);
        ls += __shfl_xor(ls, 4);
        ls += __shfl_xor(ls, 8);
        const int orow = b * SS + q0 + w * 16 + quad * 4 + reg;
#pragma unroll
        for (int dt = 0; dt < 4; ++dt)
            Op[(size_t)orow * DD + h * HD + dt * 16 + l15] = f2bf_rne(oacc[dt][reg]);
        if (l15 == 0) lp[(size_t)orow * HH + h] = ls;
    }
}

// ---------------------------------------------------------------------------
extern "C" void kernel_launch(void* const* d_in, const int* in_sizes, int n_in,
                              void* d_out, int out_size, void* d_ws, size_t ws_size,
                              hipStream_t stream) {
    const float* inp   = (const float*)d_in[0];
    const uchar_t* amask = (const uchar_t*)d_in[1];
    const int*   relm  = (const int*)d_in[2];
    const float* qkv_w = (const float*)d_in[3];
    const float* rel_A = (const float*)d_in[4];
    const float* o_w   = (const float*)d_in[5];
    const float* w1    = (const float*)d_in[6];
    const float* b1    = (const float*)d_in[7];
    const float* w2    = (const float*)d_in[8];
    const float* b2    = (const float*)d_in[9];
    const float* ln1_g = (const float*)d_in[10];
    const float* ln1_b = (const float*)d_in[11];
    const float* ln2_g = (const float*)d_in[12];
    const float* ln2_b = (const float*)d_in[13];
    float* out = (float*)d_out;

    // workspace layout
    char* p = (char*)d_ws;
    ushort_t* x_bf   = (ushort_t*)p; p += BSD * 2;
    ushort_t* h_bf   = (ushort_t*)p; p += BSD * 2;
    ushort_t* ff_bf  = (ushort_t*)p; p += (size_t)BS2 * DFF * 2;
    ushort_t* qkvw_bf= (ushort_t*)p; p += (size_t)3 * DD * DD * 2;
    ushort_t* ow_bf  = (ushort_t*)p; p += (size_t)DD * DD * 2;
    ushort_t* w1_bf  = (ushort_t*)p; p += (size_t)DFF * DD * 2;
    ushort_t* w2_bf  = (ushort_t*)p; p += (size_t)DD * DFF * 2;
    ushort_t* qkv_bf = (ushort_t*)p; p += (size_t)BS2 * 3 * DD * 2;
    float*    resid  = (float*)p;    p += BSD * 4;
    ushort_t* pool   = (ushort_t*)p; p += 4 * BSD * 2;
    ushort_t* Opart  = (ushort_t*)p; p += 2 * BSD * 2;
    float*    lpart  = (float*)p;    p += (size_t)2 * BS2 * HH * 4;
    unsigned* codes  = (unsigned*)p; p += (size_t)BB * SS * SS;

    // 0. prep1: qkv_w cvt + LN1 only (critical-path minimum)
    prep1_kernel<<<P1_CVT + P1_LN, 256, 0, stream>>>(
        qkv_w, qkvw_bf, inp, ln1_g, ln1_b, x_bf);

    // 1. QKV gemm (576 blocks) + shadow codes packing (2048 blocks)
    qkv_codes_kernel<<<QKV_G + BB * SS, 256, 0, stream>>>(
        x_bf, qkvw_bf, qkv_bf, relm, amask, codes);

    // 2. attention (768) + shadow o_w cvt only (576)
    attn_cvt_kernel<<<ATT_G + OW_BLK, 256, 0, stream>>>(
        qkv_bf, codes, rel_A, Opart, lpart, o_w, ow_bf);

    // 3. o-proj with FUSED attn merge (384) + shadow w1 cvt (2304)
    oproj_w1_kernel<<<OPJ_G + W1_BLK, 256, 0, stream>>>(
        Opart, ow_bf, pool, lpart, w1, w1_bf);

    // 4. fused: resid = inp + p0 + p1 ; h_bf = LN2(resid)
    merge2_ln_kernel<<<BS2, 256, 0, stream>>>(
        pool, inp, ln2_g, ln2_b, resid, h_bf);

    // 5. MLP1 relu gemm (768) + shadow w2 cvt (2304)
    mlp1_w2_kernel<<<M1_G + W2_BLK, 256, 0, stream>>>(
        h_bf, w1_bf, b1, ff_bf, w2, w2_bf);

    // 6. MLP2 bf16 partials (Z=4) : 768 blocks
    gemm_tile<false, false, false, true, false>
        <<<DD / 128 * 32 * 4, 256, 0, stream>>>(
        ff_bf, w2_bf, nullptr, pool, nullptr, BS2, DD, DFF, DFF / 4, DD / 128);

    // 7. out = resid + b2 + p0..p3
    merge4_kernel<<<(int)(BSD / 4 / 256), 256, 0, stream>>>(
        pool, resid, b2, out, (int)(BSD / 4));
}

// Round 13
// 246.351 us; speedup vs baseline: 1.0140x; 1.0032x over previous
//
#include <hip/hip_runtime.h>
#include <hip/hip_bf16.h>

// Problem constants
#define BB 2
#define SS 1024
#define DD 768
#define HH 12
#define HD 64
#define DFF 3072
#define EPS 1e-5f
#define BS2 (BB * SS)            // 2048
#define BSD ((size_t)BS2 * DD)   // 2048*768

typedef unsigned short ushort_t;
typedef unsigned char uchar_t;
using short8 = __attribute__((ext_vector_type(8))) short;
using f32x4  = __attribute__((ext_vector_type(4))) float;

// s_waitcnt immediates (gfx9 encoding)
#define WAITCNT_LGKM0 0xC07F     // lgkmcnt(0), vmcnt/expcnt unconstrained

__device__ __forceinline__ ushort_t f2bf_rne(float f) {
    union { float f; unsigned u; } x; x.f = f;
    unsigned r = x.u + 0x7fff + ((x.u >> 16) & 1);
    return (ushort_t)(r >> 16);
}
__device__ __forceinline__ float bf2f(short u) {
    union { unsigned i; float f; } x;
    x.i = ((unsigned)(ushort_t)u) << 16;
    return x.f;
}
// (o0 + o1) * inv, elementwise bf16x8
__device__ __forceinline__ short8 mergeo(short8 a, short8 b, float inv) {
    short8 o;
#pragma unroll
    for (int i = 0; i < 8; ++i)
        o[i] = (short)f2bf_rne((bf2f(a[i]) + bf2f(b[i])) * inv);
    return o;
}

// fp32 -> bf16 cvt of one float4-quad per thread
__device__ __forceinline__ void cvt_quad(const float* __restrict__ src, int off,
                                         ushort_t* __restrict__ dst, int i) {
    float4 v = ((const float4*)src)[off];
    ushort4 o;
    o.x = f2bf_rne(v.x); o.y = f2bf_rne(v.y);
    o.z = f2bf_rne(v.z); o.w = f2bf_rne(v.w);
    ((ushort4*)dst)[i] = o;
}

// ---------------------------------------------------------------------------
// prep1: ONLY what QKV needs — qkv_w cvt (1728 blocks) + LN1 (2048 blocks).
// ---------------------------------------------------------------------------
#define P1_CVT (3 * DD * DD / 4 / 256)   // 1728
#define P1_LN  BS2                        // 2048

__global__ __launch_bounds__(256) void prep1_kernel(
    const float* __restrict__ qkv_w, ushort_t* __restrict__ qkvw_bf,
    const float* __restrict__ x, const float* __restrict__ g,
    const float* __restrict__ b, ushort_t* __restrict__ y)
{
    const int bx = blockIdx.x;
    const int t  = threadIdx.x;
    if (bx < P1_CVT) {
        int i = bx * 256 + t;
        cvt_quad(qkv_w, i, qkvw_bf, i);
        return;
    }
    // ---- LN1 ----
    const int row = bx - P1_CVT;
    const float* xr = x + (size_t)row * DD;
    float s = 0.f, ss = 0.f;
    for (int i = t; i < DD; i += 256) {
        float v = xr[i];
        s += v; ss += v * v;
    }
    for (int off = 32; off; off >>= 1) {
        s  += __shfl_down(s,  off);
        ss += __shfl_down(ss, off);
    }
    __shared__ float reds[4], redss[4], bc[2];
    if ((t & 63) == 0) { reds[t >> 6] = s; redss[t >> 6] = ss; }
    __syncthreads();
    if (t == 0) {
        float S1 = reds[0] + reds[1] + reds[2] + reds[3];
        float S2 = redss[0] + redss[1] + redss[2] + redss[3];
        float mean = S1 / DD;
        float var = S2 / DD - mean * mean;
        bc[0] = mean;
        bc[1] = rsqrtf(var + EPS);
    }
    __syncthreads();
    float mean = bc[0], inv = bc[1];
    ushort_t* yr = y + (size_t)row * DD;
    for (int i = t; i < DD; i += 256) {
        yr[i] = f2bf_rne((xr[i] - mean) * inv * g[i] + b[i]);
    }
}

// ---------------------------------------------------------------------------
// Fused: resid = inp + p0 + p1 (bf16 partials) ; h_bf = LN(resid).
// ---------------------------------------------------------------------------
__global__ __launch_bounds__(256) void merge2_ln_kernel(
    const ushort_t* __restrict__ part, const float* __restrict__ inp,
    const float* __restrict__ g, const float* __restrict__ b,
    float* __restrict__ resid, ushort_t* __restrict__ h_bf)
{
    const int row = blockIdx.x;
    const int t = threadIdx.x;
    float4 v = make_float4(0.f, 0.f, 0.f, 0.f);
    const size_t idx = (size_t)row * (DD / 4) + t;
    if (t < DD / 4) {
        v = ((const float4*)inp)[idx];
        ushort4 p0 = ((const ushort4*)part)[idx];
        ushort4 p1 = ((const ushort4*)(part + BSD))[idx];
        v.x += bf2f(p0.x) + bf2f(p1.x);
        v.y += bf2f(p0.y) + bf2f(p1.y);
        v.z += bf2f(p0.z) + bf2f(p1.z);
        v.w += bf2f(p0.w) + bf2f(p1.w);
        ((float4*)resid)[idx] = v;
    }
    float s  = v.x + v.y + v.z + v.w;
    float ss = v.x * v.x + v.y * v.y + v.z * v.z + v.w * v.w;
    for (int off = 32; off; off >>= 1) {
        s  += __shfl_down(s,  off);
        ss += __shfl_down(ss, off);
    }
    __shared__ float reds[4], redss[4], bc[2];
    if ((t & 63) == 0) { reds[t >> 6] = s; redss[t >> 6] = ss; }
    __syncthreads();
    if (t == 0) {
        float S1 = reds[0] + reds[1] + reds[2] + reds[3];
        float S2 = redss[0] + redss[1] + redss[2] + redss[3];
        float mean = S1 / DD;
        float var = S2 / DD - mean * mean;
        bc[0] = mean;
        bc[1] = rsqrtf(var + EPS);
    }
    __syncthreads();
    if (t < DD / 4) {
        const float mean = bc[0], inv = bc[1];
        float4 gv = ((const float4*)g)[t];
        float4 bv = ((const float4*)b)[t];
        ushort4 o;
        o.x = f2bf_rne((v.x - mean) * inv * gv.x + bv.x);
        o.y = f2bf_rne((v.y - mean) * inv * gv.y + bv.y);
        o.z = f2bf_rne((v.z - mean) * inv * gv.z + bv.z);
        o.w = f2bf_rne((v.w - mean) * inv * gv.w + bv.w);
        ((ushort4*)h_bf)[idx] = o;
    }
}

// ---------------------------------------------------------------------------
// merge4: out = resid + b2 + sum of 4 bf16 partial slices.
// ---------------------------------------------------------------------------
__global__ __launch_bounds__(256) void merge4_kernel(
    const ushort_t* __restrict__ part, const float* __restrict__ resid,
    const float* __restrict__ b2, float* __restrict__ outp, int n4)
{
    int i = blockIdx.x * 256 + threadIdx.x;
    if (i >= n4) return;
    float4 v = ((const float4*)resid)[i];
    int col4 = (i * 4) % DD;
    float4 bv = *(const float4*)(b2 + col4);
    v.x += bv.x; v.y += bv.y; v.z += bv.z; v.w += bv.w;
#pragma unroll
    for (int z = 0; z < 4; ++z) {
        ushort4 pz = ((const ushort4*)(part + (size_t)z * BSD))[i];
        v.x += bf2f(pz.x); v.y += bf2f(pz.y);
        v.z += bf2f(pz.z); v.w += bf2f(pz.w);
    }
    ((float4*)outp)[i] = v;
}

// ---------------------------------------------------------------------------
// REGISTER-PIPELINED MFMA GEMM BODY (R3 core — best measured), 64x128 tile,
// BK=64, 256 threads = 4 waves, XCD-chunked swizzle with explicit gemm-block
// count `nwg` (the launch may carry extra shadow blocks after the gemm range).
// FUSE_ATT: A is the attention k-split pair merged on the fly (R5/R7 path).
// ---------------------------------------------------------------------------
template <bool RELU, bool OUT_BF16, bool HAS_BIAS, bool PARTIAL, bool FUSE_ATT>
__device__ __forceinline__ void gemm_body(
    int bid, int nwg,
    const ushort_t* __restrict__ A, const ushort_t* __restrict__ W,
    const float* __restrict__ bias, void* __restrict__ Cout,
    const float* __restrict__ lpart,
    int M, int N, int K, int Ksplit, int nx)
{
    __shared__ __align__(16) ushort_t As[512 * 8];    // 8 KB  (64 rows x 8 kq)
    __shared__ __align__(16) ushort_t Bs[1024 * 8];   // 16 KB (128 rows x 8 kq)

    // XCD-chunked decode: nwg % 8 == 0 for all our launches.
    const int swz = (bid & 7) * (nwg >> 3) + (bid >> 3);
    const int by  = swz & 31;          // ny = 32 always (M=2048, 64-row tiles)
    const int t2  = swz >> 5;
    const int bxx = t2 % nx;
    const int bz  = t2 / nx;

    const int t  = threadIdx.x;
    const int n0 = bxx * 128;
    const int m0 = by * 64;
    const int kb = bz * Ksplit;
    const int w  = t >> 6;
    const int l  = t & 63;
    const int wm = (w & 1) * 32;
    const int wn = (w >> 1) * 64;
    const int l15  = l & 15;
    const int quad = l >> 4;

    const ushort_t* gA = A + (size_t)(m0 + (t & 63)) * K + kb + (t >> 6) * 8;
    const ushort_t* gB = W + (size_t)(n0 + (t & 127)) * K + kb + (t >> 7) * 8;

    const float* lp0 = nullptr; const float* lp1 = nullptr;
    const int hbase = kb >> 6;
    if (FUSE_ATT) {
        lp0 = lpart + (size_t)(m0 + (t & 63)) * HH;
        lp1 = lp0 + (size_t)BS2 * HH;
    }

    // prologue: stage tile 0 into registers
    short8 pa0, pa1, ra0, ra1, sa0, sa1;
    float li0 = 0.f, li1 = 0.f;
    if (FUSE_ATT) {
        ra0 = *(const short8*)(gA);
        ra1 = *(const short8*)(gA + 32);
        sa0 = *(const short8*)(gA + BSD);
        sa1 = *(const short8*)(gA + BSD + 32);
        li0 = lp0[hbase];
        li1 = lp1[hbase];
    } else {
        pa0 = *(const short8*)(gA);
        pa1 = *(const short8*)(gA + 32);
    }
    short8 pb0 = *(const short8*)(gB);
    short8 pb1 = *(const short8*)(gB + 16);
    short8 pb2 = *(const short8*)(gB + 32);
    short8 pb3 = *(const short8*)(gB + 48);

    f32x4 acc[2][4] = {};
    const int nIter = Ksplit >> 6;

    for (int it = 0; it < nIter; ++it) {
        // barrier A: all waves finished reading LDS from the previous iter
        __builtin_amdgcn_s_barrier();
        if (FUSE_ATT) {
            const float inv = 1.0f / (li0 + li1);
            pa0 = mergeo(ra0, sa0, inv);
            pa1 = mergeo(ra1, sa1, inv);
        }
        // commit staged tile to LDS (compiler inserts precise vmcnt waits)
        *(short8*)&As[(size_t)t * 8]           = pa0;
        *(short8*)&As[(size_t)(t + 256) * 8]   = pa1;
        *(short8*)&Bs[(size_t)t * 8]           = pb0;
        *(short8*)&Bs[(size_t)(t + 256) * 8]   = pb1;
        *(short8*)&Bs[(size_t)(t + 512) * 8]   = pb2;
        *(short8*)&Bs[(size_t)(t + 768) * 8]   = pb3;
        // issue next tile's loads (in flight across the whole compute phase)
        if (it + 1 < nIter) {
            const int k0 = (it + 1) << 6;
            if (FUSE_ATT) {
                ra0 = *(const short8*)(gA + k0);
                ra1 = *(const short8*)(gA + k0 + 32);
                sa0 = *(const short8*)(gA + k0 + BSD);
                sa1 = *(const short8*)(gA + k0 + BSD + 32);
                li0 = lp0[hbase + it + 1];
                li1 = lp1[hbase + it + 1];
            } else {
                pa0 = *(const short8*)(gA + k0);
                pa1 = *(const short8*)(gA + k0 + 32);
            }
            pb0 = *(const short8*)(gB + k0);
            pb1 = *(const short8*)(gB + k0 + 16);
            pb2 = *(const short8*)(gB + k0 + 32);
            pb3 = *(const short8*)(gB + k0 + 48);
        }
        // my ds_writes done; barrier B: everyone's writes visible
        __builtin_amdgcn_s_waitcnt(WAITCNT_LGKM0);
        __builtin_amdgcn_s_barrier();

#pragma unroll
        for (int ks = 0; ks < 2; ++ks) {
            const ushort_t* aptr = &As[(size_t)((ks * 4 + quad) * 64 + wm + l15) * 8];
            const ushort_t* bptr = &Bs[(size_t)((ks * 4 + quad) * 128 + wn + l15) * 8];
            short8 af[2], bf[4];
#pragma unroll
            for (int i = 0; i < 2; ++i)
                af[i] = *(const short8*)(aptr + (size_t)i * 16 * 8);
#pragma unroll
            for (int j = 0; j < 4; ++j)
                bf[j] = *(const short8*)(bptr + (size_t)j * 16 * 8);
#pragma unroll
            for (int i = 0; i < 2; ++i)
#pragma unroll
                for (int j = 0; j < 4; ++j)
                    acc[i][j] = __builtin_amdgcn_mfma_f32_16x16x32_bf16(
                        af[i], bf[j], acc[i][j], 0, 0, 0);
        }
    }

    // epilogue: C/D layout col=lane&15, row=(lane>>4)*4+reg
    if (PARTIAL) {
        ushort_t* Cp = (ushort_t*)Cout + (size_t)bz * ((size_t)M * N);
#pragma unroll
        for (int i = 0; i < 2; ++i) {
            const int row = m0 + wm + i * 16 + quad * 4;
#pragma unroll
            for (int j = 0; j < 4; ++j) {
                const int col = n0 + wn + j * 16 + l15;
#pragma unroll
                for (int r = 0; r < 4; ++r)
                    Cp[(size_t)(row + r) * N + col] = f2bf_rne(acc[i][j][r]);
            }
        }
    } else {
#pragma unroll
        for (int i = 0; i < 2; ++i) {
            const int row = m0 + wm + i * 16 + quad * 4;
#pragma unroll
            for (int j = 0; j < 4; ++j) {
                const int col = n0 + wn + j * 16 + l15;
                const float bv = HAS_BIAS ? bias[col] : 0.f;
#pragma unroll
                for (int r = 0; r < 4; ++r) {
                    float v = acc[i][j][r] + bv;
                    if (RELU) v = fmaxf(v, 0.f);
                    if (OUT_BF16)
                        ((ushort_t*)Cout)[(size_t)(row + r) * N + col] = f2bf_rne(v);
                    else
                        ((float*)Cout)[(size_t)(row + r) * N + col] = v;
                }
            }
        }
    }
}

// plain gemm launch (whole grid is gemm blocks)
template <bool RELU, bool OUT_BF16, bool HAS_BIAS, bool PARTIAL, bool FUSE_ATT>
__global__ __launch_bounds__(256) void gemm_tile(
    const ushort_t* __restrict__ A, const ushort_t* __restrict__ W,
    const float* __restrict__ bias, void* __restrict__ Cout,
    const float* __restrict__ lpart,
    int M, int N, int K, int Ksplit, int nx)
{
    gemm_body<RELU, OUT_BF16, HAS_BIAS, PARTIAL, FUSE_ATT>(
        blockIdx.x, gridDim.x, A, W, bias, Cout, lpart, M, N, K, Ksplit, nx);
}

// ---------------------------------------------------------------------------
// QKV gemm + shadow-batched codes packing.
// blocks [0, QKV_G): gemm; [QKV_G, QKV_G + 2048): rel/mask -> codes.
// ---------------------------------------------------------------------------
#define QKV_G (3 * DD / 128 * 32)   // 576

__global__ __launch_bounds__(256) void qkv_codes_kernel(
    const ushort_t* __restrict__ A, const ushort_t* __restrict__ W,
    ushort_t* __restrict__ Cout,
    const int* __restrict__ rel, const uchar_t* __restrict__ mask,
    unsigned* __restrict__ codes)
{
    const int bx = blockIdx.x;
    if (bx < QKV_G) {
        gemm_body<false, true, false, false, false>(
            bx, QKV_G, A, W, nullptr, Cout, nullptr,
            BS2, 3 * DD, DD, DD, 3 * DD / 128);
        return;
    }
    const int t = threadIdx.x;
    int tid = (bx - QKV_G) * 256 + t;
    int l15 = tid & 15;
    int kt  = (tid >> 4) & 15;
    int q   = (tid >> 8) & (SS - 1);
    int bb  = tid >> 18;
    const int* rrow = rel + ((size_t)(bb * SS + q)) * SS + kt * 64 + l15;
    const uchar_t* mrow = mask + (size_t)bb * SS + kt * 64 + l15;
    unsigned o = 0;
#pragma unroll
    for (int nt = 0; nt < 4; ++nt) {
        unsigned c = mrow[nt * 16] ? 3u : (unsigned)(rrow[nt * 16] + 1);
        o |= c << (8 * nt);
    }
    codes[((size_t)(bb * SS + q) * 16 + kt) * 16 + l15] = o;
}

// ---------------------------------------------------------------------------
// o-proj (FUSE_ATT, 384 gemm blocks) + shadow w1 cvt (2304 blocks).
// ---------------------------------------------------------------------------
#define OPJ_G (DD / 128 * 32 * 2)        // 384
#define W1_BLK (DFF * DD / 4 / 256)      // 2304

__global__ __launch_bounds__(256) void oproj_w1_kernel(
    const ushort_t* __restrict__ A, const ushort_t* __restrict__ W,
    void* __restrict__ Cout, const float* __restrict__ lpart,
    const float* __restrict__ w1, ushort_t* __restrict__ w1_bf)
{
    const int bx = blockIdx.x;
    if (bx < OPJ_G) {
        gemm_body<false, false, false, true, true>(
            bx, OPJ_G, A, W, nullptr, Cout, lpart,
            BS2, DD, DD, DD / 2, DD / 128);
        return;
    }
    int i = (bx - OPJ_G) * 256 + threadIdx.x;
    cvt_quad(w1, i, w1_bf, i);
}

// ---------------------------------------------------------------------------
// MLP1 (relu gemm, 768 blocks) + shadow w2 cvt (2304 blocks).
// ---------------------------------------------------------------------------
#define M1_G (DFF / 128 * 32)            // 768
#define W2_BLK (DD * DFF / 4 / 256)      // 2304

__global__ __launch_bounds__(256) void mlp1_w2_kernel(
    const ushort_t* __restrict__ A, const ushort_t* __restrict__ W,
    const float* __restrict__ bias, void* __restrict__ Cout,
    const float* __restrict__ w2, ushort_t* __restrict__ w2_bf)
{
    const int bx = blockIdx.x;
    if (bx < M1_G) {
        gemm_body<true, true, true, false, false>(
            bx, M1_G, A, W, bias, Cout, nullptr,
            BS2, DFF, DD, DD, DFF / 128);
        return;
    }
    int i = (bx - M1_G) * 256 + threadIdx.x;
    cvt_quad(w2, i, w2_bf, i);
}

// ---------------------------------------------------------------------------
// MFMA flash attention (R13: R12 core + T5 s_setprio(1) around the QK^T and
// PV MFMA clusters — catalog-positive on attn (m191: independent blocks at
// different phases on a CU; our config: 3 blocks/CU). Everything else
// unchanged) + shadow o_w cvt (576 blocks).
// ---------------------------------------------------------------------------
#define ATT_G (BB * HH * 16 * 2)        // 768
#define OW_BLK (DD * DD / 4 / 256)      // 576

__global__ __launch_bounds__(256) void attn_cvt_kernel(
    const ushort_t* __restrict__ qkv,
    const unsigned* __restrict__ codes,
    const float* __restrict__ rel_A,
    ushort_t* __restrict__ Opart,
    float* __restrict__ lpart,
    const float* __restrict__ o_w, ushort_t* __restrict__ ow_bf)
{
    const int bx = blockIdx.x;
    const int t  = threadIdx.x;
    if (bx >= ATT_G) {
        int i = (bx - ATT_G) * 256 + t;
        cvt_quad(o_w, i, ow_bf, i);
        return;
    }

    __shared__ __align__(16) ushort_t Ks[2][64 * 64];
    __shared__ __align__(16) unsigned Vt2[2][64 * 36];
    __shared__ __align__(16) ushort_t Ps[64 * 72];
    __shared__ __align__(16) float r3s[64][4];

    const int ks = bx & 1;
    const int qt = (bx >> 1) & 15;
    const int h  = (bx >> 5) % HH;
    const int b  = bx / (32 * HH);
    const int q0 = qt * 64;
    const int w  = t >> 6;
    const int l  = t & 63;
    const int l15  = l & 15;
    const int quad = l >> 4;

    const int sr  = t >> 3;
    const int scp = t & 7;
    const int vkp = t >> 3;
    const int vdg = t & 7;
    const int vkps = vkp ^ (vdg * 4);

    const int kt0 = ks * 8;

    const size_t qrow = (size_t)(b * SS + q0 + w * 16 + l15) * (3 * DD) + h * HD;
    const short8 qf0 = *(const short8*)(qkv + qrow + quad * 8);
    const short8 qf1 = *(const short8*)(qkv + qrow + 32 + quad * 8);

    // codes base for this thread: index (qloc,kt) -> cb[qloc*256 + (kt-kt0)*16]
    const unsigned* cb = codes + ((size_t)(b * SS + q0) * 16 + kt0) * 16 + l15;
    unsigned ccur[4], cnxt[4];
#pragma unroll
    for (int reg = 0; reg < 4; ++reg) {
        const int qloc = w * 16 + quad * 4 + reg;
        ccur[reg] = cb[(size_t)qloc * 256];          // iter 0's codes, issued early
    }

    {
        float rv[3];
#pragma unroll
        for (int c = 0; c < 3; ++c) {
            const float* a = rel_A + c * HD + quad * 8;
            float acc = 0.f;
#pragma unroll
            for (int j = 0; j < 8; ++j) acc += bf2f(qf0[j]) * a[j];
#pragma unroll
            for (int j = 0; j < 8; ++j) acc += bf2f(qf1[j]) * a[32 + j];
            acc += __shfl_xor(acc, 16);
            acc += __shfl_xor(acc, 32);
            rv[c] = acc;
        }
        if (quad == 0) {
            float4 f4 = make_float4(rv[0], rv[1], rv[2], -2.4e31f);
            *(float4*)&r3s[w * 16 + l15][0] = f4;
        }
    }

    float l_run[4] = {0.f, 0.f, 0.f, 0.f};
    f32x4 oacc[4] = {};

    short8 va, vb;
    {
        const int k0 = kt0 * 64;
        const int cl  = scp ^ (sr & 7);
        const ushort_t* g = qkv + (size_t)(b * SS + k0 + sr) * (3 * DD) + DD + h * HD + cl * 8;
        __builtin_amdgcn_global_load_lds(
            (const __attribute__((address_space(1))) unsigned*)g,
            (__attribute__((address_space(3))) unsigned*)(&Ks[0][0] + (size_t)t * 8), 16, 0, 0);
        const int r2  = sr + 32;
        const int cl2 = scp ^ (r2 & 7);
        const ushort_t* g2 = qkv + (size_t)(b * SS + k0 + r2) * (3 * DD) + DD + h * HD + cl2 * 8;
        __builtin_amdgcn_global_load_lds(
            (const __attribute__((address_space(1))) unsigned*)g2,
            (__attribute__((address_space(3))) unsigned*)(&Ks[0][0] + (size_t)(t + 256) * 8), 16, 0, 0);
        const ushort_t* gv = qkv + (size_t)(b * SS + k0 + 2 * vkp) * (3 * DD) + 2 * DD + h * HD + vdg * 8;
        va = *(const short8*)gv;
        vb = *(const short8*)(gv + 3 * DD);
#pragma unroll
        for (int i = 0; i < 8; ++i)
            Vt2[0][(size_t)(vdg * 8 + i) * 36 + vkps] =
                (unsigned)(ushort_t)va[i] | ((unsigned)(ushort_t)vb[i] << 16);
    }
    __syncthreads();
    float4 r3v[4];
#pragma unroll
    for (int reg = 0; reg < 4; ++reg)
        r3v[reg] = *(const float4*)&r3s[w * 16 + quad * 4 + reg][0];

    for (int i8 = 0; i8 < 8; ++i8) {
        const int kt  = kt0 + i8;
        const int cur = i8 & 1;
        const bool more = (i8 + 1 < 8);
        if (more) {
            const int k0 = (kt + 1) * 64;
            const int nb = cur ^ 1;
            const int cl  = scp ^ (sr & 7);
            const ushort_t* g = qkv + (size_t)(b * SS + k0 + sr) * (3 * DD) + DD + h * HD + cl * 8;
            __builtin_amdgcn_global_load_lds(
                (const __attribute__((address_space(1))) unsigned*)g,
                (__attribute__((address_space(3))) unsigned*)(&Ks[nb][0] + (size_t)t * 8), 16, 0, 0);
            const int r2  = sr + 32;
            const int cl2 = scp ^ (r2 & 7);
            const ushort_t* g2 = qkv + (size_t)(b * SS + k0 + r2) * (3 * DD) + DD + h * HD + cl2 * 8;
            __builtin_amdgcn_global_load_lds(
                (const __attribute__((address_space(1))) unsigned*)g2,
                (__attribute__((address_space(3))) unsigned*)(&Ks[nb][0] + (size_t)(t + 256) * 8), 16, 0, 0);
            const ushort_t* gv = qkv + (size_t)(b * SS + k0 + 2 * vkp) * (3 * DD) + 2 * DD + h * HD + vdg * 8;
            va = *(const short8*)gv;
            vb = *(const short8*)(gv + 3 * DD);
            // prefetch next iteration's rel-codes (consumed next softmax phase)
#pragma unroll
            for (int reg = 0; reg < 4; ++reg) {
                const int qloc = w * 16 + quad * 4 + reg;
                cnxt[reg] = cb[(size_t)qloc * 256 + (size_t)(i8 + 1) * 16];
            }
        }

        f32x4 sacc[4] = {};
        __builtin_amdgcn_s_setprio(1);
#pragma unroll
        for (int kc = 0; kc < 2; ++kc) {
            const short8 qv = kc ? qf1 : qf0;
#pragma unroll
            for (int nt = 0; nt < 4; ++nt) {
                const int row = nt * 16 + l15;
                const int cp  = (kc * 4 + quad) ^ (row & 7);
                const short8 kf = *(const short8*)(&Ks[cur][0] + (size_t)row * 64 + cp * 8);
                sacc[nt] = __builtin_amdgcn_mfma_f32_16x16x32_bf16(qv, kf, sacc[nt], 0, 0, 0);
            }
        }
        __builtin_amdgcn_s_setprio(0);

#pragma unroll
        for (int reg = 0; reg < 4; ++reg) {
            const int qloc = w * 16 + quad * 4 + reg;
            const unsigned cds = ccur[reg];
            const float4 r4 = r3v[reg];
#pragma unroll
            for (int nt = 0; nt < 4; ++nt) {
                const unsigned c = (cds >> (8 * nt)) & 0xff;
                float rvv = (c == 0) ? r4.x : (c == 1) ? r4.y : (c == 2) ? r4.z : r4.w;
                const float p = __expf((sacc[nt][reg] + rvv) * 0.125f);
                l_run[reg] += p;
                Ps[(size_t)qloc * 72 + nt * 16 + l15] = f2bf_rne(p);
            }
        }

        __builtin_amdgcn_s_setprio(1);
#pragma unroll
        for (int kc = 0; kc < 2; ++kc) {
            const short8 pf = *(const short8*)(Ps + (size_t)(w * 16 + l15) * 72 + kc * 32 + quad * 8);
#pragma unroll
            for (int dt = 0; dt < 4; ++dt) {
                const int d  = dt * 16 + l15;
                const int dg = d >> 3;
                const int kps0 = (kc * 16 + quad * 4) ^ ((dg & 7) * 4);
                const short8 vf = *(const short8*)((const ushort_t*)&Vt2[cur][(size_t)d * 36 + kps0]);
                oacc[dt] = __builtin_amdgcn_mfma_f32_16x16x32_bf16(pf, vf, oacc[dt], 0, 0, 0);
            }
        }
        __builtin_amdgcn_s_setprio(0);

        if (more) {
            const int nb = cur ^ 1;
#pragma unroll
            for (int i = 0; i < 8; ++i)
                Vt2[nb][(size_t)(vdg * 8 + i) * 36 + vkps] =
                    (unsigned)(ushort_t)va[i] | ((unsigned)(ushort_t)vb[i] << 16);
#pragma unroll
            for (int reg = 0; reg < 4; ++reg)
                ccur[reg] = cnxt[reg];
            __syncthreads();
        }
    }

    ushort_t* Op = Opart + (size_t)ks * BSD;
    float* lp = lpart + (size_t)ks * BS2 * HH;
#pragma unroll
    for (int reg = 0; reg < 4; ++reg) {
        float ls = l_run[reg];
        ls += __shfl_xor(ls, 1);
        ls += __shfl_xor(ls, 2);
        ls += __shfl_xor(ls, 4);
        ls += __shfl_xor(ls, 8);
        const int orow = b * SS + q0 + w * 16 + quad * 4 + reg;
#pragma unroll
        for (int dt = 0; dt < 4; ++dt)
            Op[(size_t)orow * DD + h * HD + dt * 16 + l15] = f2bf_rne(oacc[dt][reg]);
        if (l15 == 0) lp[(size_t)orow * HH + h] = ls;
    }
}

// ---------------------------------------------------------------------------
extern "C" void kernel_launch(void* const* d_in, const int* in_sizes, int n_in,
                              void* d_out, int out_size, void* d_ws, size_t ws_size,
                              hipStream_t stream) {
    const float* inp   = (const float*)d_in[0];
    const uchar_t* amask = (const uchar_t*)d_in[1];
    const int*   relm  = (const int*)d_in[2];
    const float* qkv_w = (const float*)d_in[3];
    const float* rel_A = (const float*)d_in[4];
    const float* o_w   = (const float*)d_in[5];
    const float* w1    = (const float*)d_in[6];
    const float* b1    = (const float*)d_in[7];
    const float* w2    = (const float*)d_in[8];
    const float* b2    = (const float*)d_in[9];
    const float* ln1_g = (const float*)d_in[10];
    const float* ln1_b = (const float*)d_in[11];
    const float* ln2_g = (const float*)d_in[12];
    const float* ln2_b = (const float*)d_in[13];
    float* out = (float*)d_out;

    // workspace layout
    char* p = (char*)d_ws;
    ushort_t* x_bf   = (ushort_t*)p; p += BSD * 2;
    ushort_t* h_bf   = (ushort_t*)p; p += BSD * 2;
    ushort_t* ff_bf  = (ushort_t*)p; p += (size_t)BS2 * DFF * 2;
    ushort_t* qkvw_bf= (ushort_t*)p; p += (size_t)3 * DD * DD * 2;
    ushort_t* ow_bf  = (ushort_t*)p; p += (size_t)DD * DD * 2;
    ushort_t* w1_bf  = (ushort_t*)p; p += (size_t)DFF * DD * 2;
    ushort_t* w2_bf  = (ushort_t*)p; p += (size_t)DD * DFF * 2;
    ushort_t* qkv_bf = (ushort_t*)p; p += (size_t)BS2 * 3 * DD * 2;
    float*    resid  = (float*)p;    p += BSD * 4;
    ushort_t* pool   = (ushort_t*)p; p += 4 * BSD * 2;
    ushort_t* Opart  = (ushort_t*)p; p += 2 * BSD * 2;
    float*    lpart  = (float*)p;    p += (size_t)2 * BS2 * HH * 4;
    unsigned* codes  = (unsigned*)p; p += (size_t)BB * SS * SS;

    // 0. prep1: qkv_w cvt + LN1 only (critical-path minimum)
    prep1_kernel<<<P1_CVT + P1_LN, 256, 0, stream>>>(
        qkv_w, qkvw_bf, inp, ln1_g, ln1_b, x_bf);

    // 1. QKV gemm (576 blocks) + shadow codes packing (2048 blocks)
    qkv_codes_kernel<<<QKV_G + BB * SS, 256, 0, stream>>>(
        x_bf, qkvw_bf, qkv_bf, relm, amask, codes);

    // 2. attention (768) + shadow o_w cvt only (576)
    attn_cvt_kernel<<<ATT_G + OW_BLK, 256, 0, stream>>>(
        qkv_bf, codes, rel_A, Opart, lpart, o_w, ow_bf);

    // 3. o-proj with FUSED attn merge (384) + shadow w1 cvt (2304)
    oproj_w1_kernel<<<OPJ_G + W1_BLK, 256, 0, stream>>>(
        Opart, ow_bf, pool, lpart, w1, w1_bf);

    // 4. fused: resid = inp + p0 + p1 ; h_bf = LN2(resid)
    merge2_ln_kernel<<<BS2, 256, 0, stream>>>(
        pool, inp, ln2_g, ln2_b, resid, h_bf);

    // 5. MLP1 relu gemm (768) + shadow w2 cvt (2304)
    mlp1_w2_kernel<<<M1_G + W2_BLK, 256, 0, stream>>>(
        h_bf, w1_bf, b1, ff_bf, w2, w2_bf);

    // 6. MLP2 bf16 partials (Z=4) : 768 blocks
    gemm_tile<false, false, false, true, false>
        <<<DD / 128 * 32 * 4, 256, 0, stream>>>(
        ff_bf, w2_bf, nullptr, pool, nullptr, BS2, DD, DFF, DFF / 4, DD / 128);

    // 7. out = resid + b2 + p0..p3
    merge4_kernel<<<(int)(BSD / 4 / 256), 256, 0, stream>>>(
        pool, resid, b2, out, (int)(BSD / 4));
}

// Round 14
// 244.414 us; speedup vs baseline: 1.0221x; 1.0079x over previous
//
#include <hip/hip_runtime.h>
#include <hip/hip_bf16.h>

// Problem constants
#define BB 2
#define SS 1024
#define DD 768
#define HH 12
#define HD 64
#define DFF 3072
#define EPS 1e-5f
#define BS2 (BB * SS)            // 2048
#define BSD ((size_t)BS2 * DD)   // 2048*768

typedef unsigned short ushort_t;
typedef unsigned char uchar_t;
using short8 = __attribute__((ext_vector_type(8))) short;
using f32x4  = __attribute__((ext_vector_type(4))) float;

// s_waitcnt immediates (gfx9 encoding)
#define WAITCNT_LGKM0 0xC07F     // lgkmcnt(0), vmcnt/expcnt unconstrained

__device__ __forceinline__ ushort_t f2bf_rne(float f) {
    union { float f; unsigned u; } x; x.f = f;
    unsigned r = x.u + 0x7fff + ((x.u >> 16) & 1);
    return (ushort_t)(r >> 16);
}
__device__ __forceinline__ float bf2f(short u) {
    union { unsigned i; float f; } x;
    x.i = ((unsigned)(ushort_t)u) << 16;
    return x.f;
}
// (o0 + o1) * inv, elementwise bf16x8
__device__ __forceinline__ short8 mergeo(short8 a, short8 b, float inv) {
    short8 o;
#pragma unroll
    for (int i = 0; i < 8; ++i)
        o[i] = (short)f2bf_rne((bf2f(a[i]) + bf2f(b[i])) * inv);
    return o;
}

// fp32 -> bf16 cvt of one float4-quad per thread
__device__ __forceinline__ void cvt_quad(const float* __restrict__ src, int off,
                                         ushort_t* __restrict__ dst, int i) {
    float4 v = ((const float4*)src)[off];
    ushort4 o;
    o.x = f2bf_rne(v.x); o.y = f2bf_rne(v.y);
    o.z = f2bf_rne(v.z); o.w = f2bf_rne(v.w);
    ((ushort4*)dst)[i] = o;
}

// ---------------------------------------------------------------------------
// prep1: ONLY what QKV needs — qkv_w cvt (1728 blocks) + LN1 (2048 blocks).
// ---------------------------------------------------------------------------
#define P1_CVT (3 * DD * DD / 4 / 256)   // 1728
#define P1_LN  BS2                        // 2048

__global__ __launch_bounds__(256) void prep1_kernel(
    const float* __restrict__ qkv_w, ushort_t* __restrict__ qkvw_bf,
    const float* __restrict__ x, const float* __restrict__ g,
    const float* __restrict__ b, ushort_t* __restrict__ y)
{
    const int bx = blockIdx.x;
    const int t  = threadIdx.x;
    if (bx < P1_CVT) {
        int i = bx * 256 + t;
        cvt_quad(qkv_w, i, qkvw_bf, i);
        return;
    }
    // ---- LN1 ----
    const int row = bx - P1_CVT;
    const float* xr = x + (size_t)row * DD;
    float s = 0.f, ss = 0.f;
    for (int i = t; i < DD; i += 256) {
        float v = xr[i];
        s += v; ss += v * v;
    }
    for (int off = 32; off; off >>= 1) {
        s  += __shfl_down(s,  off);
        ss += __shfl_down(ss, off);
    }
    __shared__ float reds[4], redss[4], bc[2];
    if ((t & 63) == 0) { reds[t >> 6] = s; redss[t >> 6] = ss; }
    __syncthreads();
    if (t == 0) {
        float S1 = reds[0] + reds[1] + reds[2] + reds[3];
        float S2 = redss[0] + redss[1] + redss[2] + redss[3];
        float mean = S1 / DD;
        float var = S2 / DD - mean * mean;
        bc[0] = mean;
        bc[1] = rsqrtf(var + EPS);
    }
    __syncthreads();
    float mean = bc[0], inv = bc[1];
    ushort_t* yr = y + (size_t)row * DD;
    for (int i = t; i < DD; i += 256) {
        yr[i] = f2bf_rne((xr[i] - mean) * inv * g[i] + b[i]);
    }
}

// ---------------------------------------------------------------------------
// Fused: resid = inp + p0 + p1 (bf16 partials) ; h_bf = LN(resid).
// ---------------------------------------------------------------------------
__global__ __launch_bounds__(256) void merge2_ln_kernel(
    const ushort_t* __restrict__ part, const float* __restrict__ inp,
    const float* __restrict__ g, const float* __restrict__ b,
    float* __restrict__ resid, ushort_t* __restrict__ h_bf)
{
    const int row = blockIdx.x;
    const int t = threadIdx.x;
    float4 v = make_float4(0.f, 0.f, 0.f, 0.f);
    const size_t idx = (size_t)row * (DD / 4) + t;
    if (t < DD / 4) {
        v = ((const float4*)inp)[idx];
        ushort4 p0 = ((const ushort4*)part)[idx];
        ushort4 p1 = ((const ushort4*)(part + BSD))[idx];
        v.x += bf2f(p0.x) + bf2f(p1.x);
        v.y += bf2f(p0.y) + bf2f(p1.y);
        v.z += bf2f(p0.z) + bf2f(p1.z);
        v.w += bf2f(p0.w) + bf2f(p1.w);
        ((float4*)resid)[idx] = v;
    }
    float s  = v.x + v.y + v.z + v.w;
    float ss = v.x * v.x + v.y * v.y + v.z * v.z + v.w * v.w;
    for (int off = 32; off; off >>= 1) {
        s  += __shfl_down(s,  off);
        ss += __shfl_down(ss, off);
    }
    __shared__ float reds[4], redss[4], bc[2];
    if ((t & 63) == 0) { reds[t >> 6] = s; redss[t >> 6] = ss; }
    __syncthreads();
    if (t == 0) {
        float S1 = reds[0] + reds[1] + reds[2] + reds[3];
        float S2 = redss[0] + redss[1] + redss[2] + redss[3];
        float mean = S1 / DD;
        float var = S2 / DD - mean * mean;
        bc[0] = mean;
        bc[1] = rsqrtf(var + EPS);
    }
    __syncthreads();
    if (t < DD / 4) {
        const float mean = bc[0], inv = bc[1];
        float4 gv = ((const float4*)g)[t];
        float4 bv = ((const float4*)b)[t];
        ushort4 o;
        o.x = f2bf_rne((v.x - mean) * inv * gv.x + bv.x);
        o.y = f2bf_rne((v.y - mean) * inv * gv.y + bv.y);
        o.z = f2bf_rne((v.z - mean) * inv * gv.z + bv.z);
        o.w = f2bf_rne((v.w - mean) * inv * gv.w + bv.w);
        ((ushort4*)h_bf)[idx] = o;
    }
}

// ---------------------------------------------------------------------------
// merge4: out = resid + b2 + sum of 4 bf16 partial slices.
// ---------------------------------------------------------------------------
__global__ __launch_bounds__(256) void merge4_kernel(
    const ushort_t* __restrict__ part, const float* __restrict__ resid,
    const float* __restrict__ b2, float* __restrict__ outp, int n4)
{
    int i = blockIdx.x * 256 + threadIdx.x;
    if (i >= n4) return;
    float4 v = ((const float4*)resid)[i];
    int col4 = (i * 4) % DD;
    float4 bv = *(const float4*)(b2 + col4);
    v.x += bv.x; v.y += bv.y; v.z += bv.z; v.w += bv.w;
#pragma unroll
    for (int z = 0; z < 4; ++z) {
        ushort4 pz = ((const ushort4*)(part + (size_t)z * BSD))[i];
        v.x += bf2f(pz.x); v.y += bf2f(pz.y);
        v.z += bf2f(pz.z); v.w += bf2f(pz.w);
    }
    ((float4*)outp)[i] = v;
}

// ---------------------------------------------------------------------------
// REGISTER-PIPELINED MFMA GEMM BODY (R3 core — best measured), 64x128 tile,
// BK=64, 256 threads = 4 waves, XCD-chunked swizzle with explicit gemm-block
// count `nwg` (the launch may carry extra shadow blocks after the gemm range).
// FUSE_ATT: A is the attention k-split pair merged on the fly (R5/R7 path).
// ---------------------------------------------------------------------------
template <bool RELU, bool OUT_BF16, bool HAS_BIAS, bool PARTIAL, bool FUSE_ATT>
__device__ __forceinline__ void gemm_body(
    int bid, int nwg,
    const ushort_t* __restrict__ A, const ushort_t* __restrict__ W,
    const float* __restrict__ bias, void* __restrict__ Cout,
    const float* __restrict__ lpart,
    int M, int N, int K, int Ksplit, int nx)
{
    __shared__ __align__(16) ushort_t As[512 * 8];    // 8 KB  (64 rows x 8 kq)
    __shared__ __align__(16) ushort_t Bs[1024 * 8];   // 16 KB (128 rows x 8 kq)

    // XCD-chunked decode: nwg % 8 == 0 for all our launches.
    const int swz = (bid & 7) * (nwg >> 3) + (bid >> 3);
    const int by  = swz & 31;          // ny = 32 always (M=2048, 64-row tiles)
    const int t2  = swz >> 5;
    const int bxx = t2 % nx;
    const int bz  = t2 / nx;

    const int t  = threadIdx.x;
    const int n0 = bxx * 128;
    const int m0 = by * 64;
    const int kb = bz * Ksplit;
    const int w  = t >> 6;
    const int l  = t & 63;
    const int wm = (w & 1) * 32;
    const int wn = (w >> 1) * 64;
    const int l15  = l & 15;
    const int quad = l >> 4;

    const ushort_t* gA = A + (size_t)(m0 + (t & 63)) * K + kb + (t >> 6) * 8;
    const ushort_t* gB = W + (size_t)(n0 + (t & 127)) * K + kb + (t >> 7) * 8;

    const float* lp0 = nullptr; const float* lp1 = nullptr;
    const int hbase = kb >> 6;
    if (FUSE_ATT) {
        lp0 = lpart + (size_t)(m0 + (t & 63)) * HH;
        lp1 = lp0 + (size_t)BS2 * HH;
    }

    // prologue: stage tile 0 into registers
    short8 pa0, pa1, ra0, ra1, sa0, sa1;
    float li0 = 0.f, li1 = 0.f;
    if (FUSE_ATT) {
        ra0 = *(const short8*)(gA);
        ra1 = *(const short8*)(gA + 32);
        sa0 = *(const short8*)(gA + BSD);
        sa1 = *(const short8*)(gA + BSD + 32);
        li0 = lp0[hbase];
        li1 = lp1[hbase];
    } else {
        pa0 = *(const short8*)(gA);
        pa1 = *(const short8*)(gA + 32);
    }
    short8 pb0 = *(const short8*)(gB);
    short8 pb1 = *(const short8*)(gB + 16);
    short8 pb2 = *(const short8*)(gB + 32);
    short8 pb3 = *(const short8*)(gB + 48);

    f32x4 acc[2][4] = {};
    const int nIter = Ksplit >> 6;

    for (int it = 0; it < nIter; ++it) {
        // barrier A: all waves finished reading LDS from the previous iter
        __builtin_amdgcn_s_barrier();
        if (FUSE_ATT) {
            const float inv = 1.0f / (li0 + li1);
            pa0 = mergeo(ra0, sa0, inv);
            pa1 = mergeo(ra1, sa1, inv);
        }
        // commit staged tile to LDS (compiler inserts precise vmcnt waits)
        *(short8*)&As[(size_t)t * 8]           = pa0;
        *(short8*)&As[(size_t)(t + 256) * 8]   = pa1;
        *(short8*)&Bs[(size_t)t * 8]           = pb0;
        *(short8*)&Bs[(size_t)(t + 256) * 8]   = pb1;
        *(short8*)&Bs[(size_t)(t + 512) * 8]   = pb2;
        *(short8*)&Bs[(size_t)(t + 768) * 8]   = pb3;
        // issue next tile's loads (in flight across the whole compute phase)
        if (it + 1 < nIter) {
            const int k0 = (it + 1) << 6;
            if (FUSE_ATT) {
                ra0 = *(const short8*)(gA + k0);
                ra1 = *(const short8*)(gA + k0 + 32);
                sa0 = *(const short8*)(gA + k0 + BSD);
                sa1 = *(const short8*)(gA + k0 + BSD + 32);
                li0 = lp0[hbase + it + 1];
                li1 = lp1[hbase + it + 1];
            } else {
                pa0 = *(const short8*)(gA + k0);
                pa1 = *(const short8*)(gA + k0 + 32);
            }
            pb0 = *(const short8*)(gB + k0);
            pb1 = *(const short8*)(gB + k0 + 16);
            pb2 = *(const short8*)(gB + k0 + 32);
            pb3 = *(const short8*)(gB + k0 + 48);
        }
        // my ds_writes done; barrier B: everyone's writes visible
        __builtin_amdgcn_s_waitcnt(WAITCNT_LGKM0);
        __builtin_amdgcn_s_barrier();

#pragma unroll
        for (int ks = 0; ks < 2; ++ks) {
            const ushort_t* aptr = &As[(size_t)((ks * 4 + quad) * 64 + wm + l15) * 8];
            const ushort_t* bptr = &Bs[(size_t)((ks * 4 + quad) * 128 + wn + l15) * 8];
            short8 af[2], bf[4];
#pragma unroll
            for (int i = 0; i < 2; ++i)
                af[i] = *(const short8*)(aptr + (size_t)i * 16 * 8);
#pragma unroll
            for (int j = 0; j < 4; ++j)
                bf[j] = *(const short8*)(bptr + (size_t)j * 16 * 8);
#pragma unroll
            for (int i = 0; i < 2; ++i)
#pragma unroll
                for (int j = 0; j < 4; ++j)
                    acc[i][j] = __builtin_amdgcn_mfma_f32_16x16x32_bf16(
                        af[i], bf[j], acc[i][j], 0, 0, 0);
        }
    }

    // epilogue: C/D layout col=lane&15, row=(lane>>4)*4+reg
    if (PARTIAL) {
        ushort_t* Cp = (ushort_t*)Cout + (size_t)bz * ((size_t)M * N);
#pragma unroll
        for (int i = 0; i < 2; ++i) {
            const int row = m0 + wm + i * 16 + quad * 4;
#pragma unroll
            for (int j = 0; j < 4; ++j) {
                const int col = n0 + wn + j * 16 + l15;
#pragma unroll
                for (int r = 0; r < 4; ++r)
                    Cp[(size_t)(row + r) * N + col] = f2bf_rne(acc[i][j][r]);
            }
        }
    } else {
#pragma unroll
        for (int i = 0; i < 2; ++i) {
            const int row = m0 + wm + i * 16 + quad * 4;
#pragma unroll
            for (int j = 0; j < 4; ++j) {
                const int col = n0 + wn + j * 16 + l15;
                const float bv = HAS_BIAS ? bias[col] : 0.f;
#pragma unroll
                for (int r = 0; r < 4; ++r) {
                    float v = acc[i][j][r] + bv;
                    if (RELU) v = fmaxf(v, 0.f);
                    if (OUT_BF16)
                        ((ushort_t*)Cout)[(size_t)(row + r) * N + col] = f2bf_rne(v);
                    else
                        ((float*)Cout)[(size_t)(row + r) * N + col] = v;
                }
            }
        }
    }
}

// plain gemm launch (whole grid is gemm blocks)
template <bool RELU, bool OUT_BF16, bool HAS_BIAS, bool PARTIAL, bool FUSE_ATT>
__global__ __launch_bounds__(256) void gemm_tile(
    const ushort_t* __restrict__ A, const ushort_t* __restrict__ W,
    const float* __restrict__ bias, void* __restrict__ Cout,
    const float* __restrict__ lpart,
    int M, int N, int K, int Ksplit, int nx)
{
    gemm_body<RELU, OUT_BF16, HAS_BIAS, PARTIAL, FUSE_ATT>(
        blockIdx.x, gridDim.x, A, W, bias, Cout, lpart, M, N, K, Ksplit, nx);
}

// ---------------------------------------------------------------------------
// QKV gemm + shadow-batched codes packing.
// blocks [0, QKV_G): gemm; [QKV_G, QKV_G + 2048): rel/mask -> codes.
// ---------------------------------------------------------------------------
#define QKV_G (3 * DD / 128 * 32)   // 576

__global__ __launch_bounds__(256) void qkv_codes_kernel(
    const ushort_t* __restrict__ A, const ushort_t* __restrict__ W,
    ushort_t* __restrict__ Cout,
    const int* __restrict__ rel, const uchar_t* __restrict__ mask,
    unsigned* __restrict__ codes)
{
    const int bx = blockIdx.x;
    if (bx < QKV_G) {
        gemm_body<false, true, false, false, false>(
            bx, QKV_G, A, W, nullptr, Cout, nullptr,
            BS2, 3 * DD, DD, DD, 3 * DD / 128);
        return;
    }
    const int t = threadIdx.x;
    int tid = (bx - QKV_G) * 256 + t;
    int l15 = tid & 15;
    int kt  = (tid >> 4) & 15;
    int q   = (tid >> 8) & (SS - 1);
    int bb  = tid >> 18;
    const int* rrow = rel + ((size_t)(bb * SS + q)) * SS + kt * 64 + l15;
    const uchar_t* mrow = mask + (size_t)bb * SS + kt * 64 + l15;
    unsigned o = 0;
#pragma unroll
    for (int nt = 0; nt < 4; ++nt) {
        unsigned c = mrow[nt * 16] ? 3u : (unsigned)(rrow[nt * 16] + 1);
        o |= c << (8 * nt);
    }
    codes[((size_t)(bb * SS + q) * 16 + kt) * 16 + l15] = o;
}

// ---------------------------------------------------------------------------
// o-proj (FUSE_ATT, 384 gemm blocks) + shadow w1 cvt (2304 blocks).
// ---------------------------------------------------------------------------
#define OPJ_G (DD / 128 * 32 * 2)        // 384
#define W1_BLK (DFF * DD / 4 / 256)      // 2304

__global__ __launch_bounds__(256) void oproj_w1_kernel(
    const ushort_t* __restrict__ A, const ushort_t* __restrict__ W,
    void* __restrict__ Cout, const float* __restrict__ lpart,
    const float* __restrict__ w1, ushort_t* __restrict__ w1_bf)
{
    const int bx = blockIdx.x;
    if (bx < OPJ_G) {
        gemm_body<false, false, false, true, true>(
            bx, OPJ_G, A, W, nullptr, Cout, lpart,
            BS2, DD, DD, DD / 2, DD / 128);
        return;
    }
    int i = (bx - OPJ_G) * 256 + threadIdx.x;
    cvt_quad(w1, i, w1_bf, i);
}

// ---------------------------------------------------------------------------
// MLP1 (relu gemm, 768 blocks) + shadow w2 cvt (2304 blocks).
// ---------------------------------------------------------------------------
#define M1_G (DFF / 128 * 32)            // 768
#define W2_BLK (DD * DFF / 4 / 256)      // 2304

__global__ __launch_bounds__(256) void mlp1_w2_kernel(
    const ushort_t* __restrict__ A, const ushort_t* __restrict__ W,
    const float* __restrict__ bias, void* __restrict__ Cout,
    const float* __restrict__ w2, ushort_t* __restrict__ w2_bf)
{
    const int bx = blockIdx.x;
    if (bx < M1_G) {
        gemm_body<true, true, true, false, false>(
            bx, M1_G, A, W, bias, Cout, nullptr,
            BS2, DFF, DD, DD, DFF / 128);
        return;
    }
    int i = (bx - M1_G) * 256 + threadIdx.x;
    cvt_quad(w2, i, w2_bf, i);
}

// ---------------------------------------------------------------------------
// MFMA flash attention (R14: R13 core + HALF-SPLIT softmax||PV interleave —
// PV kc=0 consumes only Ps cols 0-31 (= softmax nt 0,1) and PV kc=1 only
// cols 32-63 (= nt 2,3); issuing PV kc=0's MFMAs right after the first
// softmax half lets the second half's VALU/exp overlap the MFMA-pipe
// latency (separate pipes). Ps is wave-private; pure reorder, identical
// values) + shadow o_w cvt (576 blocks).
// ---------------------------------------------------------------------------
#define ATT_G (BB * HH * 16 * 2)        // 768
#define OW_BLK (DD * DD / 4 / 256)      // 576

__global__ __launch_bounds__(256) void attn_cvt_kernel(
    const ushort_t* __restrict__ qkv,
    const unsigned* __restrict__ codes,
    const float* __restrict__ rel_A,
    ushort_t* __restrict__ Opart,
    float* __restrict__ lpart,
    const float* __restrict__ o_w, ushort_t* __restrict__ ow_bf)
{
    const int bx = blockIdx.x;
    const int t  = threadIdx.x;
    if (bx >= ATT_G) {
        int i = (bx - ATT_G) * 256 + t;
        cvt_quad(o_w, i, ow_bf, i);
        return;
    }

    __shared__ __align__(16) ushort_t Ks[2][64 * 64];
    __shared__ __align__(16) unsigned Vt2[2][64 * 36];
    __shared__ __align__(16) ushort_t Ps[64 * 72];
    __shared__ __align__(16) float r3s[64][4];

    const int ks = bx & 1;
    const int qt = (bx >> 1) & 15;
    const int h  = (bx >> 5) % HH;
    const int b  = bx / (32 * HH);
    const int q0 = qt * 64;
    const int w  = t >> 6;
    const int l  = t & 63;
    const int l15  = l & 15;
    const int quad = l >> 4;

    const int sr  = t >> 3;
    const int scp = t & 7;
    const int vkp = t >> 3;
    const int vdg = t & 7;
    const int vkps = vkp ^ (vdg * 4);

    const int kt0 = ks * 8;

    const size_t qrow = (size_t)(b * SS + q0 + w * 16 + l15) * (3 * DD) + h * HD;
    const short8 qf0 = *(const short8*)(qkv + qrow + quad * 8);
    const short8 qf1 = *(const short8*)(qkv + qrow + 32 + quad * 8);

    // codes base for this thread: index (qloc,kt) -> cb[qloc*256 + (kt-kt0)*16]
    const unsigned* cb = codes + ((size_t)(b * SS + q0) * 16 + kt0) * 16 + l15;
    unsigned ccur[4], cnxt[4];
#pragma unroll
    for (int reg = 0; reg < 4; ++reg) {
        const int qloc = w * 16 + quad * 4 + reg;
        ccur[reg] = cb[(size_t)qloc * 256];          // iter 0's codes, issued early
    }

    {
        float rv[3];
#pragma unroll
        for (int c = 0; c < 3; ++c) {
            const float* a = rel_A + c * HD + quad * 8;
            float acc = 0.f;
#pragma unroll
            for (int j = 0; j < 8; ++j) acc += bf2f(qf0[j]) * a[j];
#pragma unroll
            for (int j = 0; j < 8; ++j) acc += bf2f(qf1[j]) * a[32 + j];
            acc += __shfl_xor(acc, 16);
            acc += __shfl_xor(acc, 32);
            rv[c] = acc;
        }
        if (quad == 0) {
            float4 f4 = make_float4(rv[0], rv[1], rv[2], -2.4e31f);
            *(float4*)&r3s[w * 16 + l15][0] = f4;
        }
    }

    float l_run[4] = {0.f, 0.f, 0.f, 0.f};
    f32x4 oacc[4] = {};

    short8 va, vb;
    {
        const int k0 = kt0 * 64;
        const int cl  = scp ^ (sr & 7);
        const ushort_t* g = qkv + (size_t)(b * SS + k0 + sr) * (3 * DD) + DD + h * HD + cl * 8;
        __builtin_amdgcn_global_load_lds(
            (const __attribute__((address_space(1))) unsigned*)g,
            (__attribute__((address_space(3))) unsigned*)(&Ks[0][0] + (size_t)t * 8), 16, 0, 0);
        const int r2  = sr + 32;
        const int cl2 = scp ^ (r2 & 7);
        const ushort_t* g2 = qkv + (size_t)(b * SS + k0 + r2) * (3 * DD) + DD + h * HD + cl2 * 8;
        __builtin_amdgcn_global_load_lds(
            (const __attribute__((address_space(1))) unsigned*)g2,
            (__attribute__((address_space(3))) unsigned*)(&Ks[0][0] + (size_t)(t + 256) * 8), 16, 0, 0);
        const ushort_t* gv = qkv + (size_t)(b * SS + k0 + 2 * vkp) * (3 * DD) + 2 * DD + h * HD + vdg * 8;
        va = *(const short8*)gv;
        vb = *(const short8*)(gv + 3 * DD);
#pragma unroll
        for (int i = 0; i < 8; ++i)
            Vt2[0][(size_t)(vdg * 8 + i) * 36 + vkps] =
                (unsigned)(ushort_t)va[i] | ((unsigned)(ushort_t)vb[i] << 16);
    }
    __syncthreads();
    float4 r3v[4];
#pragma unroll
    for (int reg = 0; reg < 4; ++reg)
        r3v[reg] = *(const float4*)&r3s[w * 16 + quad * 4 + reg][0];

    for (int i8 = 0; i8 < 8; ++i8) {
        const int kt  = kt0 + i8;
        const int cur = i8 & 1;
        const bool more = (i8 + 1 < 8);
        if (more) {
            const int k0 = (kt + 1) * 64;
            const int nb = cur ^ 1;
            const int cl  = scp ^ (sr & 7);
            const ushort_t* g = qkv + (size_t)(b * SS + k0 + sr) * (3 * DD) + DD + h * HD + cl * 8;
            __builtin_amdgcn_global_load_lds(
                (const __attribute__((address_space(1))) unsigned*)g,
                (__attribute__((address_space(3))) unsigned*)(&Ks[nb][0] + (size_t)t * 8), 16, 0, 0);
            const int r2  = sr + 32;
            const int cl2 = scp ^ (r2 & 7);
            const ushort_t* g2 = qkv + (size_t)(b * SS + k0 + r2) * (3 * DD) + DD + h * HD + cl2 * 8;
            __builtin_amdgcn_global_load_lds(
                (const __attribute__((address_space(1))) unsigned*)g2,
                (__attribute__((address_space(3))) unsigned*)(&Ks[nb][0] + (size_t)(t + 256) * 8), 16, 0, 0);
            const ushort_t* gv = qkv + (size_t)(b * SS + k0 + 2 * vkp) * (3 * DD) + 2 * DD + h * HD + vdg * 8;
            va = *(const short8*)gv;
            vb = *(const short8*)(gv + 3 * DD);
            // prefetch next iteration's rel-codes (consumed next softmax phase)
#pragma unroll
            for (int reg = 0; reg < 4; ++reg) {
                const int qloc = w * 16 + quad * 4 + reg;
                cnxt[reg] = cb[(size_t)qloc * 256 + (size_t)(i8 + 1) * 16];
            }
        }

        f32x4 sacc[4] = {};
        __builtin_amdgcn_s_setprio(1);
#pragma unroll
        for (int kc = 0; kc < 2; ++kc) {
            const short8 qv = kc ? qf1 : qf0;
#pragma unroll
            for (int nt = 0; nt < 4; ++nt) {
                const int row = nt * 16 + l15;
                const int cp  = (kc * 4 + quad) ^ (row & 7);
                const short8 kf = *(const short8*)(&Ks[cur][0] + (size_t)row * 64 + cp * 8);
                sacc[nt] = __builtin_amdgcn_mfma_f32_16x16x32_bf16(qv, kf, sacc[nt], 0, 0, 0);
            }
        }
        __builtin_amdgcn_s_setprio(0);

        // HALF-SPLIT softmax || PV: PV kc=half consumes only Ps cols
        // [half*32, half*32+32) = softmax nt {2*half, 2*half+1}. Issuing
        // PV(half=0) right after the first softmax half lets the second
        // half's exp/VALU overlap the MFMA-pipe latency.
#pragma unroll
        for (int half = 0; half < 2; ++half) {
            // softmax for nt = 2*half, 2*half+1 (8 elements/thread)
#pragma unroll
            for (int reg = 0; reg < 4; ++reg) {
                const int qloc = w * 16 + quad * 4 + reg;
                const unsigned cds = ccur[reg];
                const float4 r4 = r3v[reg];
#pragma unroll
                for (int nn = 0; nn < 2; ++nn) {
                    const int nt = half * 2 + nn;
                    const unsigned c = (cds >> (8 * nt)) & 0xff;
                    float rvv = (c == 0) ? r4.x : (c == 1) ? r4.y : (c == 2) ? r4.z : r4.w;
                    const float p = __expf((sacc[nt][reg] + rvv) * 0.125f);
                    l_run[reg] += p;
                    Ps[(size_t)qloc * 72 + nt * 16 + l15] = f2bf_rne(p);
                }
            }
            // PV for kc = half
            const short8 pf = *(const short8*)(Ps + (size_t)(w * 16 + l15) * 72 + half * 32 + quad * 8);
            __builtin_amdgcn_s_setprio(1);
#pragma unroll
            for (int dt = 0; dt < 4; ++dt) {
                const int d  = dt * 16 + l15;
                const int dg = d >> 3;
                const int kps0 = (half * 16 + quad * 4) ^ ((dg & 7) * 4);
                const short8 vf = *(const short8*)((const ushort_t*)&Vt2[cur][(size_t)d * 36 + kps0]);
                oacc[dt] = __builtin_amdgcn_mfma_f32_16x16x32_bf16(pf, vf, oacc[dt], 0, 0, 0);
            }
            __builtin_amdgcn_s_setprio(0);
        }

        if (more) {
            const int nb = cur ^ 1;
#pragma unroll
            for (int i = 0; i < 8; ++i)
                Vt2[nb][(size_t)(vdg * 8 + i) * 36 + vkps] =
                    (unsigned)(ushort_t)va[i] | ((unsigned)(ushort_t)vb[i] << 16);
#pragma unroll
            for (int reg = 0; reg < 4; ++reg)
                ccur[reg] = cnxt[reg];
            __syncthreads();
        }
    }

    ushort_t* Op = Opart + (size_t)ks * BSD;
    float* lp = lpart + (size_t)ks * BS2 * HH;
#pragma unroll
    for (int reg = 0; reg < 4; ++reg) {
        float ls = l_run[reg];
        ls += __shfl_xor(ls, 1);
        ls += __shfl_xor(ls, 2);
        ls += __shfl_xor(ls, 4);
        ls += __shfl_xor(ls, 8);
        const int orow = b * SS + q0 + w * 16 + quad * 4 + reg;
#pragma unroll
        for (int dt = 0; dt < 4; ++dt)
            Op[(size_t)orow * DD + h * HD + dt * 16 + l15] = f2bf_rne(oacc[dt][reg]);
        if (l15 == 0) lp[(size_t)orow * HH + h] = ls;
    }
}

// ---------------------------------------------------------------------------
extern "C" void kernel_launch(void* const* d_in, const int* in_sizes, int n_in,
                              void* d_out, int out_size, void* d_ws, size_t ws_size,
                              hipStream_t stream) {
    const float* inp   = (const float*)d_in[0];
    const uchar_t* amask = (const uchar_t*)d_in[1];
    const int*   relm  = (const int*)d_in[2];
    const float* qkv_w = (const float*)d_in[3];
    const float* rel_A = (const float*)d_in[4];
    const float* o_w   = (const float*)d_in[5];
    const float* w1    = (const float*)d_in[6];
    const float* b1    = (const float*)d_in[7];
    const float* w2    = (const float*)d_in[8];
    const float* b2    = (const float*)d_in[9];
    const float* ln1_g = (const float*)d_in[10];
    const float* ln1_b = (const float*)d_in[11];
    const float* ln2_g = (const float*)d_in[12];
    const float* ln2_b = (const float*)d_in[13];
    float* out = (float*)d_out;

    // workspace layout
    char* p = (char*)d_ws;
    ushort_t* x_bf   = (ushort_t*)p; p += BSD * 2;
    ushort_t* h_bf   = (ushort_t*)p; p += BSD * 2;
    ushort_t* ff_bf  = (ushort_t*)p; p += (size_t)BS2 * DFF * 2;
    ushort_t* qkvw_bf= (ushort_t*)p; p += (size_t)3 * DD * DD * 2;
    ushort_t* ow_bf  = (ushort_t*)p; p += (size_t)DD * DD * 2;
    ushort_t* w1_bf  = (ushort_t*)p; p += (size_t)DFF * DD * 2;
    ushort_t* w2_bf  = (ushort_t*)p; p += (size_t)DD * DFF * 2;
    ushort_t* qkv_bf = (ushort_t*)p; p += (size_t)BS2 * 3 * DD * 2;
    float*    resid  = (float*)p;    p += BSD * 4;
    ushort_t* pool   = (ushort_t*)p; p += 4 * BSD * 2;
    ushort_t* Opart  = (ushort_t*)p; p += 2 * BSD * 2;
    float*    lpart  = (float*)p;    p += (size_t)2 * BS2 * HH * 4;
    unsigned* codes  = (unsigned*)p; p += (size_t)BB * SS * SS;

    // 0. prep1: qkv_w cvt + LN1 only (critical-path minimum)
    prep1_kernel<<<P1_CVT + P1_LN, 256, 0, stream>>>(
        qkv_w, qkvw_bf, inp, ln1_g, ln1_b, x_bf);

    // 1. QKV gemm (576 blocks) + shadow codes packing (2048 blocks)
    qkv_codes_kernel<<<QKV_G + BB * SS, 256, 0, stream>>>(
        x_bf, qkvw_bf, qkv_bf, relm, amask, codes);

    // 2. attention (768) + shadow o_w cvt only (576)
    attn_cvt_kernel<<<ATT_G + OW_BLK, 256, 0, stream>>>(
        qkv_bf, codes, rel_A, Opart, lpart, o_w, ow_bf);

    // 3. o-proj with FUSED attn merge (384) + shadow w1 cvt (2304)
    oproj_w1_kernel<<<OPJ_G + W1_BLK, 256, 0, stream>>>(
        Opart, ow_bf, pool, lpart, w1, w1_bf);

    // 4. fused: resid = inp + p0 + p1 ; h_bf = LN2(resid)
    merge2_ln_kernel<<<BS2, 256, 0, stream>>>(
        pool, inp, ln2_g, ln2_b, resid, h_bf);

    // 5. MLP1 relu gemm (768) + shadow w2 cvt (2304)
    mlp1_w2_kernel<<<M1_G + W2_BLK, 256, 0, stream>>>(
        h_bf, w1_bf, b1, ff_bf, w2, w2_bf);

    // 6. MLP2 bf16 partials (Z=4) : 768 blocks
    gemm_tile<false, false, false, true, false>
        <<<DD / 128 * 32 * 4, 256, 0, stream>>>(
        ff_bf, w2_bf, nullptr, pool, nullptr, BS2, DD, DFF, DFF / 4, DD / 128);

    // 7. out = resid + b2 + p0..p3
    merge4_kernel<<<(int)(BSD / 4 / 256), 256, 0, stream>>>(
        pool, resid, b2, out, (int)(BSD / 4));
}